// Round 5
// baseline (797.790 us; speedup 1.0000x reference)
//
#include <hip/hip_runtime.h>
#include <hip/hip_bf16.h>
#include <cstdint>
#include <math.h>

#define B_ 32
#define T_ 336
#define N_ 321
#define L_ 2
#define E_ 4
#define F_ 2048
#define P_ 96
#define TPAD 352   // T padded to multiple of 32 (K of GEMM1 / proj stage1)
#define NPAD 384   // N padded to multiple of 128 (M tiles)
#define TTPAD 384  // T padded to multiple of 96/128 (N tiles of GEMM2)

typedef __hip_bfloat16 bf16;
typedef __attribute__((ext_vector_type(8))) __bf16 bf16x8;
typedef __attribute__((ext_vector_type(4))) float f32x4;

__device__ __forceinline__ void async_copy16(const void* g, void* l) {
  __builtin_amdgcn_global_load_lds(
      (__attribute__((address_space(1))) void*)(uintptr_t)g,
      (__attribute__((address_space(3))) void*)(unsigned int)(uintptr_t)l,
      16, 0, 0);
}

// LDS chunk layout (k-outer): chunk = 16 rows x 32 cols stored as
//   element_offset = chunk*512 + colgroup*128 + row*8   (colgroup = k/8)
// Frag read (row=l15, colgroup=quad) -> byte = chunk*1024 + quad*256 + l15*16:
// banks spread 2-way max (free). Staging lane l writes LDS lane-linear l*16,
// so source addr uses row = lane&15, colgroup = lane>>4.

// ---------------- transpose + cast fp32 -> bf16 (K-contiguous operand prep) ----------
__global__ void transpose_cast_kernel(const float* __restrict__ src, bf16* __restrict__ dst,
                                      int R, int C, int Rp, int Cp,
                                      long long sStride, long long dStride) {
  __shared__ float tile[32][33];
  const float* s = src + (size_t)blockIdx.z * sStride;
  bf16* d = dst + (size_t)blockIdx.z * dStride;
  int r0 = blockIdx.x * 32, c0 = blockIdx.y * 32;
  int tx = threadIdx.x, ty = threadIdx.y;
  #pragma unroll
  for (int ii = 0; ii < 4; ii++) {
    int rl = ty * 4 + ii;
    int r = r0 + rl, c = c0 + tx;
    tile[rl][tx] = (r < R && c < C) ? s[(size_t)r * C + c] : 0.f;
  }
  __syncthreads();
  #pragma unroll
  for (int ii = 0; ii < 4; ii++) {
    int cl = ty * 4 + ii;
    int cd = c0 + cl, rd = r0 + tx;
    if (cd < Cp && rd < Rp)
      d[(size_t)cd * Rp + rd] = __float2bfloat16(tile[tx][cl]);
  }
}

// ---------------- RevIN over time axis: out[b,t,n] = (x[b,t,n,0]-mu)/sd -------------
__global__ void revin_kernel(const float* __restrict__ x, float* __restrict__ out) {
  int b = blockIdx.x;
  int n = blockIdx.y * 192 + threadIdx.x;
  if (n >= N_) return;
  const float* xp = x + ((size_t)b * T_ * N_ + n) * 3;
  float s1 = 0.f, s2 = 0.f;
  for (int t = 0; t < T_; t++) {
    float v = xp[(size_t)t * N_ * 3];
    s1 += v; s2 += v * v;
  }
  float mu = s1 / T_;
  float var = s2 / T_ - mu * mu;
  float inv = 1.f / sqrtf(var + 1e-5f);
  for (int t = 0; t < T_; t++) {
    float v = (xp[(size_t)t * N_ * 3] - mu) * inv;
    out[((size_t)b * T_ + t) * N_ + n] = v;
  }
}

// ---------------- pack: out (+= P0+P1 + gated be2) -> out, Abuf bf16 (B,NPAD,TPAD) --
#define PSLAB ((size_t)B_ * T_ * N_)
__global__ void pack_kernel(float* __restrict__ out, bf16* __restrict__ Abuf,
                            const float* __restrict__ be2, const float* __restrict__ P,
                            const int* __restrict__ pair_e, const float* __restrict__ pair_gate,
                            int layer) {
  __shared__ float tile[32][33];
  int b = blockIdx.z;
  int t0 = blockIdx.x * 32, n0 = blockIdx.y * 32;
  int tx = threadIdx.x, ty = threadIdx.y;
  bool dob = layer >= 0;
  float g0 = 0.f, g1 = 0.f; int e0 = 0, e1 = 0;
  if (dob) {
    e0 = pair_e[b * 2]; e1 = pair_e[b * 2 + 1];
    g0 = pair_gate[b * 2]; g1 = pair_gate[b * 2 + 1];
  }
  #pragma unroll
  for (int ii = 0; ii < 4; ii++) {
    int i = ty * 4 + ii;
    int t = t0 + i, n = n0 + tx;
    float v = 0.f;
    if (t < T_ && n < N_) {
      size_t q = ((size_t)b * T_ + t) * N_ + n;
      v = out[q];
      if (dob) {
        v += P[q] + P[PSLAB + q];   // split-expert partial merge
        v += g0 * be2[(layer * E_ + e0) * T_ + t] + g1 * be2[(layer * E_ + e1) * T_ + t];
        out[q] = v;
      }
    }
    tile[i][tx] = v;
  }
  __syncthreads();
  #pragma unroll
  for (int ii = 0; ii < 4; ii++) {
    int i = ty * 4 + ii;           // n-local
    int n = n0 + i, t = t0 + tx;
    if (n < NPAD && t < TPAD)
      Abuf[((size_t)b * NPAD + n) * TPAD + t] = __float2bfloat16(tile[tx][i]);
  }
}

// ---------------- gating: logits[b,e] = (mean_n out[b,t,n]) @ Wg[l] -----------------
__global__ void gate1_kernel(const float* __restrict__ out, const float* __restrict__ Wg,
                             float* __restrict__ logits, int layer) {
  __shared__ float red[4][512];
  int b = blockIdx.x, tid = threadIdx.x; // 384 threads
  float cm = 0.f;
  if (tid < T_) {
    const float* p = out + ((size_t)b * T_ + tid) * N_;
    float s = 0.f;
    for (int n = 0; n < N_; n++) s += p[n];
    cm = s / (float)N_;
  }
  #pragma unroll
  for (int e = 0; e < 4; e++)
    red[e][tid] = (tid < T_) ? cm * Wg[(layer * T_ + tid) * E_ + e] : 0.f;
  if (tid < 128) {
    #pragma unroll
    for (int e = 0; e < 4; e++) red[e][384 + tid] = 0.f;
  }
  __syncthreads();
  for (int s = 256; s > 0; s >>= 1) {
    if (tid < s) {
      #pragma unroll
      for (int e = 0; e < 4; e++) red[e][tid] += red[e][tid + s];
    }
    __syncthreads();
  }
  if (tid < 4) logits[b * 4 + tid] = red[tid][0];
}

// top-2 + softmax + importance + cv^2 loss
__global__ void gate2_kernel(const float* __restrict__ logits, int* __restrict__ pair_e,
                             float* __restrict__ pair_gate, float* __restrict__ loss_partial,
                             int layer) {
  __shared__ float gates[32][4];
  __shared__ float imp[4];
  int tid = threadIdx.x;
  if (tid < 32) {
    float v[4];
    #pragma unroll
    for (int e = 0; e < 4; e++) v[e] = logits[tid * 4 + e];
    int i0 = 0;
    for (int e = 1; e < 4; e++) if (v[e] > v[i0]) i0 = e;     // lowest index wins ties
    int i1 = -1;
    for (int e = 0; e < 4; e++) {
      if (e == i0) continue;
      if (i1 < 0 || v[e] > v[i1]) i1 = e;
    }
    float ex = expf(v[i1] - v[i0]);
    float g0 = 1.f / (1.f + ex);
    float g1 = ex / (1.f + ex);
    pair_e[tid * 2] = i0; pair_e[tid * 2 + 1] = i1;
    pair_gate[tid * 2] = g0; pair_gate[tid * 2 + 1] = g1;
    #pragma unroll
    for (int e = 0; e < 4; e++) gates[tid][e] = 0.f;
    gates[tid][i0] = g0; gates[tid][i1] = g1;
  }
  __syncthreads();
  if (tid < 4) {
    float s = 0.f;
    for (int bb = 0; bb < 32; bb++) s += gates[bb][tid];
    imp[tid] = s;
  }
  __syncthreads();
  if (tid == 0) {
    float m = (imp[0] + imp[1] + imp[2] + imp[3]) * 0.25f;
    float va = 0.f;
    #pragma unroll
    for (int e = 0; e < 4; e++) { float d = imp[e] - m; va += d * d; }
    va *= 0.25f;
    loss_partial[layer] = 0.01f * (va / (m * m + 1e-10f));
  }
}

// ---------------- GEMM1: h[pair] = gate * relu(Abuf[b] @ We1[l,e] + be1) ------------
__global__ __launch_bounds__(256) void gemm1_kernel(
    const bf16* __restrict__ Abuf, const bf16* __restrict__ W1T,
    const float* __restrict__ be1, const int* __restrict__ pair_e,
    const float* __restrict__ pair_gate, bf16* __restrict__ h, int layer) {
  __shared__ __align__(16) bf16 As[128 * 32];
  __shared__ __align__(16) bf16 Bs[128 * 32];
  __shared__ float bias_s[128];

  const int tid = threadIdx.x;
  const int w = tid >> 6, lane = tid & 63;
  const int pair = blockIdx.z;
  const int b = pair >> 1;
  const int e = pair_e[pair];
  const float gate = pair_gate[pair];
  const int m0 = blockIdx.y * 128;  // n-dim
  const int f0 = blockIdx.x * 128;

  const bf16* Ag = Abuf + (size_t)b * NPAD * TPAD + (size_t)m0 * TPAD;
  const bf16* Bg = W1T + ((size_t)(layer * E_ + e) * F_ + f0) * TPAD;
  if (tid < 128) bias_s[tid] = be1[(size_t)(layer * E_ + e) * F_ + f0 + tid];

  f32x4 acc[4][4];
  const f32x4 zero = {0.f, 0.f, 0.f, 0.f};
  #pragma unroll
  for (int i = 0; i < 4; i++)
    #pragma unroll
    for (int j = 0; j < 4; j++) acc[i][j] = zero;

  const int wm = w >> 1, wn = w & 1;
  const int srow = lane & 15;          // staging source row within chunk
  const int scg8 = (lane >> 4) * 8;    // staging source col-group offset
  const int quad = lane >> 4;
  const int l15 = lane & 15;

  for (int kk = 0; kk < TPAD / 32; ++kk) {
    const int k0 = kk * 32;
    #pragma unroll
    for (int i = 0; i < 2; i++) {
      int r = (w * 2 + i) * 16 + srow;
      async_copy16(Ag + (size_t)r * TPAD + k0 + scg8, As + (w * 2 + i) * 512);
    }
    #pragma unroll
    for (int i = 0; i < 2; i++) {
      int r = (w * 2 + i) * 16 + srow;
      async_copy16(Bg + (size_t)r * TPAD + k0 + scg8, Bs + (w * 2 + i) * 512);
    }
    __syncthreads();
    bf16x8 af[4], bfr[4];
    #pragma unroll
    for (int mi = 0; mi < 4; mi++)
      af[mi] = *(const bf16x8*)(As + (wm * 4 + mi) * 512 + quad * 128 + l15 * 8);
    #pragma unroll
    for (int ni = 0; ni < 4; ni++)
      bfr[ni] = *(const bf16x8*)(Bs + (wn * 4 + ni) * 512 + quad * 128 + l15 * 8);
    #pragma unroll
    for (int mi = 0; mi < 4; mi++)
      #pragma unroll
      for (int ni = 0; ni < 4; ni++)
        acc[mi][ni] = __builtin_amdgcn_mfma_f32_16x16x32_bf16(af[mi], bfr[ni], acc[mi][ni], 0, 0, 0);
    __syncthreads();
  }

  // epilogue: bias + relu + gate, LDS transpose for coalesced bf16 stores
  bf16* tw0 = As + w * 1024;
  bf16* tw1 = Bs + w * 1024;
  size_t hbase = (size_t)pair * NPAD * F_ + f0 + wn * 64;
  #pragma unroll
  for (int mi = 0; mi < 4; mi++) {
    bf16* tw = (mi & 1) ? tw1 : tw0;
    #pragma unroll
    for (int ni = 0; ni < 4; ni++) {
      float bias = bias_s[wn * 64 + ni * 16 + l15];
      #pragma unroll
      for (int r = 0; r < 4; r++) {
        float v = acc[mi][ni][r] + bias;
        v = fmaxf(v, 0.f) * gate;
        tw[(quad * 4 + r) * 64 + ni * 16 + l15] = __float2bfloat16(v);
      }
    }
    int row = lane >> 2;            // 0..15
    int fpart = (lane & 3) * 16;    // 0,16,32,48
    int ng = m0 + wm * 64 + mi * 16 + row;
    const uint4* sp = (const uint4*)(tw + row * 64 + fpart);
    uint4 d0 = sp[0];
    uint4 d1 = sp[1];
    uint4* dp = (uint4*)(h + hbase + (size_t)ng * F_ + fpart);
    dp[0] = d0; dp[1] = d1;
  }
}

// ---------------- GEMM2 (split-expert): P[j][b,t,n] = h[b*2+j] @ We2[l,e_j] ---------
// One expert per block (K=2048, BK=64). Tile 64(n) x 96(t). grid (4, 6, 64).
// 1536 blocks = 6/CU; LDS 20KB. Plain stores, outputs disjoint.
__global__ __launch_bounds__(256) void gemm2_kernel(
    const bf16* __restrict__ h, const bf16* __restrict__ W2T,
    const int* __restrict__ pair_e, float* __restrict__ P, int layer) {
  __shared__ __align__(16) bf16 As2[2][4 * 512];   // 8KB: 64 rows x 32 cols per half
  __shared__ __align__(16) bf16 Bs2[2][6 * 512];   // 12KB: 96 rows x 32 cols per half
  const int tid = threadIdx.x;
  const int w = tid >> 6, lane = tid & 63;
  const int pair = blockIdx.z;
  const int b = pair >> 1, j = pair & 1;
  const int n0 = blockIdx.y * 64;
  const int t0 = blockIdx.x * 96;
  const int e = pair_e[pair];
  const bf16* Ag = h + (size_t)pair * NPAD * F_ + (size_t)n0 * F_;
  const bf16* Bg = W2T + ((size_t)(layer * E_ + e) * TTPAD + t0) * F_;
  const int srow = lane & 15, scg8 = (lane >> 4) * 8;
  const int quad = lane >> 4, l15 = lane & 15;
  const int wm = w >> 1, wt = w & 1;   // wave tile: 32(n) x 48(t)

  f32x4 acc[2][3];
  const f32x4 zero = {0.f, 0.f, 0.f, 0.f};
  #pragma unroll
  for (int i = 0; i < 2; i++)
    #pragma unroll
    for (int jj = 0; jj < 3; jj++) acc[i][jj] = zero;

  for (int kk = 0; kk < F_ / 64; ++kk) {   // 32 iterations, BK=64
    #pragma unroll
    for (int hh = 0; hh < 2; hh++) {
      const int fl = kk * 64 + hh * 32 + scg8;
      // A: 4 chunks, one per wave
      async_copy16(Ag + (size_t)(w * 16 + srow) * F_ + fl, &As2[hh][w * 512]);
      // B: 6 chunks: wave w stages chunk w; waves 0,1 also stage chunks 4,5
      async_copy16(Bg + (size_t)(w * 16 + srow) * F_ + fl, &Bs2[hh][w * 512]);
      if (w < 2)
        async_copy16(Bg + (size_t)((w + 4) * 16 + srow) * F_ + fl, &Bs2[hh][(w + 4) * 512]);
    }
    __syncthreads();
    #pragma unroll
    for (int hh = 0; hh < 2; hh++) {
      bf16x8 af[2], bfr[3];
      #pragma unroll
      for (int mi = 0; mi < 2; mi++)
        af[mi] = *(const bf16x8*)(&As2[hh][(wm * 2 + mi) * 512 + quad * 128 + l15 * 8]);
      #pragma unroll
      for (int ni = 0; ni < 3; ni++)
        bfr[ni] = *(const bf16x8*)(&Bs2[hh][(wt * 3 + ni) * 512 + quad * 128 + l15 * 8]);
      #pragma unroll
      for (int mi = 0; mi < 2; mi++)
        #pragma unroll
        for (int ni = 0; ni < 3; ni++)
          acc[mi][ni] = __builtin_amdgcn_mfma_f32_16x16x32_bf16(af[mi], bfr[ni], acc[mi][ni], 0, 0, 0);
    }
    __syncthreads();
  }

  float* Pj = P + (size_t)j * PSLAB;
  #pragma unroll
  for (int mi = 0; mi < 2; mi++) {
    #pragma unroll
    for (int ni = 0; ni < 3; ni++) {
      int n = n0 + wm * 32 + mi * 16 + quad * 4;
      int t = t0 + wt * 48 + ni * 16 + l15;
      if (t < T_) {
        float* po = Pj + ((size_t)b * T_ + t) * N_ + n;
        #pragma unroll
        for (int r = 0; r < 4; r++)
          if (n + r < N_) po[r] = acc[mi][ni][r];
      }
    }
  }
}

// ---------------- projection head: fused two-stage MFMA -----------------------------
#define HS_STRIDE 104  // 96 + 8 pad (208B row stride, 16B-aligned; 2-way aliasing free)
__global__ __launch_bounds__(256) void proj_kernel(
    const bf16* __restrict__ Abuf, const bf16* __restrict__ P1T, const float* __restrict__ P1b,
    const bf16* __restrict__ P2T, const float* __restrict__ P2b,
    const float* __restrict__ loss_partial, float* __restrict__ dout) {
  __shared__ __align__(16) bf16 Hs[128 * HS_STRIDE];
  const int tid = threadIdx.x;
  const int w = tid >> 6, lane = tid & 63;
  const int quad = lane >> 4, l15 = lane & 15;
  const int b = blockIdx.y;
  const int m0 = blockIdx.x * 128;

  f32x4 acc1[2][6];
  const f32x4 zero = {0.f, 0.f, 0.f, 0.f};
  #pragma unroll
  for (int i = 0; i < 2; i++)
    #pragma unroll
    for (int j = 0; j < 6; j++) acc1[i][j] = zero;

  const bf16* Arow = Abuf + ((size_t)b * NPAD + m0 + w * 32) * TPAD;
  for (int kk = 0; kk < TPAD / 32; ++kk) {
    bf16x8 af[2], bfr[6];
    #pragma unroll
    for (int mi = 0; mi < 2; mi++)
      af[mi] = *(const bf16x8*)(Arow + (size_t)(mi * 16 + l15) * TPAD + kk * 32 + quad * 8);
    #pragma unroll
    for (int ni = 0; ni < 6; ni++)
      bfr[ni] = *(const bf16x8*)(P1T + (size_t)(ni * 16 + l15) * TPAD + kk * 32 + quad * 8);
    #pragma unroll
    for (int mi = 0; mi < 2; mi++)
      #pragma unroll
      for (int ni = 0; ni < 6; ni++)
        acc1[mi][ni] = __builtin_amdgcn_mfma_f32_16x16x32_bf16(af[mi], bfr[ni], acc1[mi][ni], 0, 0, 0);
  }

  #pragma unroll
  for (int mi = 0; mi < 2; mi++) {
    #pragma unroll
    for (int ni = 0; ni < 6; ni++) {
      float bias = P1b[ni * 16 + l15];
      #pragma unroll
      for (int r = 0; r < 4; r++) {
        float x = acc1[mi][ni][r] + bias;
        float t = 1.f - 2.f / (__expf(2.f * x) + 1.f);
        Hs[(w * 32 + mi * 16 + quad * 4 + r) * HS_STRIDE + ni * 16 + l15] = __float2bfloat16(t);
      }
    }
  }
  __syncthreads();

  #pragma unroll
  for (int half = 0; half < 2; ++half) {
    f32x4 acc2[2][6];
    #pragma unroll
    for (int i = 0; i < 2; i++)
      #pragma unroll
      for (int j = 0; j < 6; j++) acc2[i][j] = zero;

    #pragma unroll
    for (int kk = 0; kk < 3; ++kk) {
      bf16x8 af[2], bfr[6];
      #pragma unroll
      for (int mi = 0; mi < 2; mi++)
        af[mi] = *(const bf16x8*)(Hs + (w * 32 + mi * 16 + l15) * HS_STRIDE + kk * 32 + quad * 8);
      #pragma unroll
      for (int ni = 0; ni < 6; ni++)
        bfr[ni] = *(const bf16x8*)(P2T + (size_t)((half * 6 + ni) * 16 + l15) * P_ + kk * 32 + quad * 8);
      #pragma unroll
      for (int mi = 0; mi < 2; mi++)
        #pragma unroll
        for (int ni = 0; ni < 6; ni++)
          acc2[mi][ni] = __builtin_amdgcn_mfma_f32_16x16x32_bf16(af[mi], bfr[ni], acc2[mi][ni], 0, 0, 0);
    }

    #pragma unroll
    for (int mi = 0; mi < 2; mi++) {
      #pragma unroll
      for (int ni = 0; ni < 6; ni++) {
        int jj = (half * 6 + ni) * 16 + l15;
        float bias = P2b[jj];
        int pout = jj >> 1;
        #pragma unroll
        for (int r = 0; r < 4; r++) {
          int n = m0 + w * 32 + mi * 16 + quad * 4 + r;
          if (n < N_) {
            float s = acc2[mi][ni][r] + bias;
            size_t o = ((size_t)b * P_ + pout) * N_ + n;
            if ((jj & 1) == 0) {
              dout[o] = s;
            } else {
              float sp = (s > 20.f) ? s : log1pf(__expf(s));
              dout[(size_t)B_ * P_ * N_ + 1 + o] = sp + 1e-6f;
            }
          }
        }
      }
    }
  }
  if (b == 0 && blockIdx.x == 0 && tid == 0)
    dout[(size_t)B_ * P_ * N_] = loss_partial[0] + loss_partial[1];
}

// ----------------------------------------------------------------------------------
extern "C" void kernel_launch(void* const* d_in, const int* in_sizes, int n_in,
                              void* d_out, int out_size, void* d_ws, size_t ws_size,
                              hipStream_t stream) {
  const float* x   = (const float*)d_in[0];
  const float* Wg  = (const float*)d_in[11];
  const float* We1 = (const float*)d_in[12];
  const float* be1 = (const float*)d_in[13];
  const float* We2 = (const float*)d_in[14];
  const float* be2 = (const float*)d_in[15];
  const float* P1w = (const float*)d_in[16];
  const float* P1b = (const float*)d_in[17];
  const float* P2w = (const float*)d_in[18];
  const float* P2b = (const float*)d_in[19];

  char* ws = (char*)d_ws;
  size_t off = 0;
  auto alloc = [&](size_t bytes) -> void* {
    void* p = ws + off;
    off += (bytes + 255) & ~(size_t)255;
    return p;
  };
  float* out        = (float*)alloc((size_t)B_ * T_ * N_ * 4);
  bf16*  Abuf       = (bf16*) alloc((size_t)B_ * NPAD * TPAD * 2);
  bf16*  W1T        = (bf16*) alloc((size_t)L_ * E_ * F_ * TPAD * 2);
  bf16*  W2T        = (bf16*) alloc((size_t)L_ * E_ * TTPAD * F_ * 2);
  bf16*  P1T        = (bf16*) alloc((size_t)P_ * TPAD * 2);
  bf16*  P2T        = (bf16*) alloc((size_t)2 * P_ * P_ * 2);
  bf16*  h          = (bf16*) alloc((size_t)B_ * 2 * NPAD * F_ * 2);
  float* Ppart      = (float*)alloc((size_t)2 * B_ * T_ * N_ * 4);
  float* logits     = (float*)alloc(B_ * E_ * 4);
  int*   pair_e     = (int*)  alloc(B_ * 2 * 4);
  float* pair_gate  = (float*)alloc(B_ * 2 * 4);
  float* loss_part  = (float*)alloc(2 * 4);
  if (ws_size < off) return;  // workspace too small — bail instead of corrupting

  dim3 tb(32, 8);
  transpose_cast_kernel<<<dim3(11, 64, 8), tb, 0, stream>>>(
      We1, W1T, T_, F_, TPAD, F_, (long long)T_ * F_, (long long)F_ * TPAD);
  transpose_cast_kernel<<<dim3(64, 12, 8), tb, 0, stream>>>(
      We2, W2T, F_, T_, F_, TTPAD, (long long)F_ * T_, (long long)TTPAD * F_);
  transpose_cast_kernel<<<dim3(11, 3, 1), tb, 0, stream>>>(
      P1w, P1T, T_, P_, TPAD, P_, 0, 0);
  transpose_cast_kernel<<<dim3(3, 6, 1), tb, 0, stream>>>(
      P2w, P2T, P_, 2 * P_, P_, 2 * P_, 0, 0);

  revin_kernel<<<dim3(B_, 2), 192, 0, stream>>>(x, out);
  pack_kernel<<<dim3(11, 12, B_), tb, 0, stream>>>(out, Abuf, be2, Ppart, pair_e, pair_gate, -1);

  for (int l = 0; l < L_; ++l) {
    gate1_kernel<<<B_, 384, 0, stream>>>(out, Wg, logits, l);
    gate2_kernel<<<1, 64, 0, stream>>>(logits, pair_e, pair_gate, loss_part, l);
    gemm1_kernel<<<dim3(16, 3, 64), 256, 0, stream>>>(Abuf, W1T, be1, pair_e, pair_gate, h, l);
    gemm2_kernel<<<dim3(4, 6, 64), 256, 0, stream>>>(h, W2T, pair_e, Ppart, l);
    pack_kernel<<<dim3(11, 12, B_), tb, 0, stream>>>(out, Abuf, be2, Ppart, pair_e, pair_gate, l);
  }

  proj_kernel<<<dim3(3, B_), 256, 0, stream>>>(Abuf, P1T, P1b, P2T, P2b, loss_part,
                                               (float*)d_out);
}

// Round 6
// 761.411 us; speedup vs baseline: 1.0478x; 1.0478x over previous
//
#include <hip/hip_runtime.h>
#include <hip/hip_bf16.h>
#include <cstdint>
#include <math.h>

#define B_ 32
#define T_ 336
#define N_ 321
#define L_ 2
#define E_ 4
#define F_ 2048
#define P_ 96
#define TPAD 352   // T padded to multiple of 32 (K of GEMM1 / proj stage1)
#define NPAD 384   // N padded to multiple of 128 (M tiles)
#define TTPAD 384  // T padded to multiple of 96/128 (N tiles of GEMM2)

typedef __hip_bfloat16 bf16;
typedef __attribute__((ext_vector_type(8))) __bf16 bf16x8;
typedef __attribute__((ext_vector_type(4))) float f32x4;

__device__ __forceinline__ void async_copy16(const void* g, void* l) {
  __builtin_amdgcn_global_load_lds(
      (__attribute__((address_space(1))) void*)(uintptr_t)g,
      (__attribute__((address_space(3))) void*)(unsigned int)(uintptr_t)l,
      16, 0, 0);
}

// LDS chunk layout (k-outer): chunk = 16 rows x 32 cols stored as
//   element_offset = chunk*512 + colgroup*128 + row*8   (colgroup = k/8)
// Frag read (row=l15, colgroup=quad): banks spread <=2-way (free, m136).
// Staging source addr uses row=lane&15, colgroup=lane>>4 (LDS dest lane-linear).

// ---------------- transpose + cast fp32 -> bf16 (K-contiguous operand prep) ----------
__global__ void transpose_cast_kernel(const float* __restrict__ src, bf16* __restrict__ dst,
                                      int R, int C, int Rp, int Cp,
                                      long long sStride, long long dStride) {
  __shared__ float tile[32][33];
  const float* s = src + (size_t)blockIdx.z * sStride;
  bf16* d = dst + (size_t)blockIdx.z * dStride;
  int r0 = blockIdx.x * 32, c0 = blockIdx.y * 32;
  int tx = threadIdx.x, ty = threadIdx.y;
  #pragma unroll
  for (int ii = 0; ii < 4; ii++) {
    int rl = ty * 4 + ii;
    int r = r0 + rl, c = c0 + tx;
    tile[rl][tx] = (r < R && c < C) ? s[(size_t)r * C + c] : 0.f;
  }
  __syncthreads();
  #pragma unroll
  for (int ii = 0; ii < 4; ii++) {
    int cl = ty * 4 + ii;
    int cd = c0 + cl, rd = r0 + tx;
    if (cd < Cp && rd < Rp)
      d[(size_t)cd * Rp + rd] = __float2bfloat16(tile[tx][cl]);
  }
}

// ---------------- RevIN over time axis: out[b,t,n] = (x[b,t,n,0]-mu)/sd -------------
__global__ void revin_kernel(const float* __restrict__ x, float* __restrict__ out) {
  int b = blockIdx.x;
  int n = blockIdx.y * 192 + threadIdx.x;
  if (n >= N_) return;
  const float* xp = x + ((size_t)b * T_ * N_ + n) * 3;
  float s1 = 0.f, s2 = 0.f;
  for (int t = 0; t < T_; t++) {
    float v = xp[(size_t)t * N_ * 3];
    s1 += v; s2 += v * v;
  }
  float mu = s1 / T_;
  float var = s2 / T_ - mu * mu;
  float inv = 1.f / sqrtf(var + 1e-5f);
  for (int t = 0; t < T_; t++) {
    float v = (xp[(size_t)t * N_ * 3] - mu) * inv;
    out[((size_t)b * T_ + t) * N_ + n] = v;
  }
}

// ---------------- initial pack: out -> Abuf bf16 (B,NPAD,TPAD), zero-padded ---------
__global__ void pack_kernel(const float* __restrict__ out, bf16* __restrict__ Abuf) {
  __shared__ float tile[32][33];
  int b = blockIdx.z;
  int t0 = blockIdx.x * 32, n0 = blockIdx.y * 32;
  int tx = threadIdx.x, ty = threadIdx.y;
  #pragma unroll
  for (int ii = 0; ii < 4; ii++) {
    int i = ty * 4 + ii;
    int t = t0 + i, n = n0 + tx;
    tile[i][tx] = (t < T_ && n < N_) ? out[((size_t)b * T_ + t) * N_ + n] : 0.f;
  }
  __syncthreads();
  #pragma unroll
  for (int ii = 0; ii < 4; ii++) {
    int i = ty * 4 + ii;           // n-local
    int n = n0 + i, t = t0 + tx;
    if (n < NPAD && t < TPAD)
      Abuf[((size_t)b * NPAD + n) * TPAD + t] = __float2bfloat16(tile[tx][i]);
  }
}

// ---------------- gating: logits[b,e] = (mean_n out[b,t,n]) @ Wg[l] -----------------
__global__ void gate1_kernel(const float* __restrict__ out, const float* __restrict__ Wg,
                             float* __restrict__ logits, int layer) {
  __shared__ float red[4][512];
  int b = blockIdx.x, tid = threadIdx.x; // 384 threads
  float cm = 0.f;
  if (tid < T_) {
    const float* p = out + ((size_t)b * T_ + tid) * N_;
    float s = 0.f;
    for (int n = 0; n < N_; n++) s += p[n];
    cm = s / (float)N_;
  }
  #pragma unroll
  for (int e = 0; e < 4; e++)
    red[e][tid] = (tid < T_) ? cm * Wg[(layer * T_ + tid) * E_ + e] : 0.f;
  if (tid < 128) {
    #pragma unroll
    for (int e = 0; e < 4; e++) red[e][384 + tid] = 0.f;
  }
  __syncthreads();
  for (int s = 256; s > 0; s >>= 1) {
    if (tid < s) {
      #pragma unroll
      for (int e = 0; e < 4; e++) red[e][tid] += red[e][tid + s];
    }
    __syncthreads();
  }
  if (tid < 4) logits[b * 4 + tid] = red[tid][0];
}

// top-2 + softmax + importance + cv^2 loss
__global__ void gate2_kernel(const float* __restrict__ logits, int* __restrict__ pair_e,
                             float* __restrict__ pair_gate, float* __restrict__ loss_partial,
                             int layer) {
  __shared__ float gates[32][4];
  __shared__ float imp[4];
  int tid = threadIdx.x;
  if (tid < 32) {
    float v[4];
    #pragma unroll
    for (int e = 0; e < 4; e++) v[e] = logits[tid * 4 + e];
    int i0 = 0;
    for (int e = 1; e < 4; e++) if (v[e] > v[i0]) i0 = e;     // lowest index wins ties
    int i1 = -1;
    for (int e = 0; e < 4; e++) {
      if (e == i0) continue;
      if (i1 < 0 || v[e] > v[i1]) i1 = e;
    }
    float ex = expf(v[i1] - v[i0]);
    float g0 = 1.f / (1.f + ex);
    float g1 = ex / (1.f + ex);
    pair_e[tid * 2] = i0; pair_e[tid * 2 + 1] = i1;
    pair_gate[tid * 2] = g0; pair_gate[tid * 2 + 1] = g1;
    #pragma unroll
    for (int e = 0; e < 4; e++) gates[tid][e] = 0.f;
    gates[tid][i0] = g0; gates[tid][i1] = g1;
  }
  __syncthreads();
  if (tid < 4) {
    float s = 0.f;
    for (int bb = 0; bb < 32; bb++) s += gates[bb][tid];
    imp[tid] = s;
  }
  __syncthreads();
  if (tid == 0) {
    float m = (imp[0] + imp[1] + imp[2] + imp[3]) * 0.25f;
    float va = 0.f;
    #pragma unroll
    for (int e = 0; e < 4; e++) { float d = imp[e] - m; va += d * d; }
    va *= 0.25f;
    loss_partial[layer] = 0.01f * (va / (m * m + 1e-10f));
  }
}

// ---------------- GEMM1: h[pair] = gate * relu(Abuf[b] @ We1[l,e] + be1) ------------
__global__ __launch_bounds__(256) void gemm1_kernel(
    const bf16* __restrict__ Abuf, const bf16* __restrict__ W1T,
    const float* __restrict__ be1, const int* __restrict__ pair_e,
    const float* __restrict__ pair_gate, bf16* __restrict__ h, int layer) {
  __shared__ __align__(16) bf16 As[128 * 32];
  __shared__ __align__(16) bf16 Bs[128 * 32];
  __shared__ float bias_s[128];

  const int tid = threadIdx.x;
  const int w = tid >> 6, lane = tid & 63;
  const int pair = blockIdx.z;
  const int b = pair >> 1;
  const int e = pair_e[pair];
  const float gate = pair_gate[pair];
  const int m0 = blockIdx.y * 128;  // n-dim
  const int f0 = blockIdx.x * 128;

  const bf16* Ag = Abuf + (size_t)b * NPAD * TPAD + (size_t)m0 * TPAD;
  const bf16* Bg = W1T + ((size_t)(layer * E_ + e) * F_ + f0) * TPAD;
  if (tid < 128) bias_s[tid] = be1[(size_t)(layer * E_ + e) * F_ + f0 + tid];

  f32x4 acc[4][4];
  const f32x4 zero = {0.f, 0.f, 0.f, 0.f};
  #pragma unroll
  for (int i = 0; i < 4; i++)
    #pragma unroll
    for (int j = 0; j < 4; j++) acc[i][j] = zero;

  const int wm = w >> 1, wn = w & 1;
  const int srow = lane & 15;          // staging source row within chunk
  const int scg8 = (lane >> 4) * 8;    // staging source col-group offset
  const int quad = lane >> 4;
  const int l15 = lane & 15;

  for (int kk = 0; kk < TPAD / 32; ++kk) {
    const int k0 = kk * 32;
    #pragma unroll
    for (int i = 0; i < 2; i++) {
      int r = (w * 2 + i) * 16 + srow;
      async_copy16(Ag + (size_t)r * TPAD + k0 + scg8, As + (w * 2 + i) * 512);
    }
    #pragma unroll
    for (int i = 0; i < 2; i++) {
      int r = (w * 2 + i) * 16 + srow;
      async_copy16(Bg + (size_t)r * TPAD + k0 + scg8, Bs + (w * 2 + i) * 512);
    }
    __syncthreads();
    bf16x8 af[4], bfr[4];
    #pragma unroll
    for (int mi = 0; mi < 4; mi++)
      af[mi] = *(const bf16x8*)(As + (wm * 4 + mi) * 512 + quad * 128 + l15 * 8);
    #pragma unroll
    for (int ni = 0; ni < 4; ni++)
      bfr[ni] = *(const bf16x8*)(Bs + (wn * 4 + ni) * 512 + quad * 128 + l15 * 8);
    #pragma unroll
    for (int mi = 0; mi < 4; mi++)
      #pragma unroll
      for (int ni = 0; ni < 4; ni++)
        acc[mi][ni] = __builtin_amdgcn_mfma_f32_16x16x32_bf16(af[mi], bfr[ni], acc[mi][ni], 0, 0, 0);
    __syncthreads();
  }

  // epilogue: bias + relu + gate, LDS transpose for coalesced bf16 stores
  bf16* tw0 = As + w * 1024;
  bf16* tw1 = Bs + w * 1024;
  size_t hbase = (size_t)pair * NPAD * F_ + f0 + wn * 64;
  #pragma unroll
  for (int mi = 0; mi < 4; mi++) {
    bf16* tw = (mi & 1) ? tw1 : tw0;
    #pragma unroll
    for (int ni = 0; ni < 4; ni++) {
      float bias = bias_s[wn * 64 + ni * 16 + l15];
      #pragma unroll
      for (int r = 0; r < 4; r++) {
        float v = acc[mi][ni][r] + bias;
        v = fmaxf(v, 0.f) * gate;
        tw[(quad * 4 + r) * 64 + ni * 16 + l15] = __float2bfloat16(v);
      }
    }
    int row = lane >> 2;            // 0..15
    int fpart = (lane & 3) * 16;    // 0,16,32,48
    int ng = m0 + wm * 64 + mi * 16 + row;
    const uint4* sp = (const uint4*)(tw + row * 64 + fpart);
    uint4 d0 = sp[0];
    uint4 d1 = sp[1];
    uint4* dp = (uint4*)(h + hbase + (size_t)ng * F_ + fpart);
    dp[0] = d0; dp[1] = d1;
  }
}

// ---------------- GEMM2+pack fused: both experts per block, K=4096 ------------------
// out[b,t,n] += h[b*2+0] @ We2[e0] + h[b*2+1] @ We2[e1] + g0*be2[e0] + g1*be2[e1]
// and Abuf[b,n,t] = bf16(out) for the next layer / proj.
// Tile 64(n) x 96(t), BK=64. Linear grid 768 with XCD swizzle: the 4 t-tiles of a
// (b,n)-group land on the SAME XCD (id spaced by 8 under round-robin dispatch) so the
// shared A-slab is served by one L2. Perf heuristic only; correctness unaffected.
#define CT_STRIDE 104
__global__ __launch_bounds__(256) void gemm2_kernel(
    const bf16* __restrict__ h, const bf16* __restrict__ W2T,
    const float* __restrict__ be2, const int* __restrict__ pair_e,
    const float* __restrict__ pair_gate, float* __restrict__ out,
    bf16* __restrict__ Abuf, int layer) {
  // S: loop = As2(2 x 4chunks) + Bs2(2 x 6chunks) = 10240 elems (20KB);
  //    epilogue reuses first 64*CT_STRIDE = 6656 elems as bf16 C-tile.
  __shared__ __align__(16) bf16 S[10240];
  __shared__ float bias_t[96];
  bf16* As2 = S;               // [hh*2048 + chunk*512 + ...]
  bf16* Bs2 = S + 4096;        // [hh*3072 + chunk*512 + ...]

  const int tid = threadIdx.x;
  const int w = tid >> 6, lane = tid & 63;
  const int id = blockIdx.x;           // 0..767
  const int u = id & 7;                // XCD (round-robin heuristic)
  const int v = id >> 3;               // 0..95
  const int tt = v & 3;
  const int pn = u + 8 * (v >> 2);     // 0..191
  const int b = pn / 6, nt = pn % 6;
  const int n0 = nt * 64, t0 = tt * 96;

  const int e0 = pair_e[b * 2], e1 = pair_e[b * 2 + 1];
  const float g0 = pair_gate[b * 2], g1 = pair_gate[b * 2 + 1];
  const bf16* A0 = h + (size_t)(b * 2) * NPAD * F_ + (size_t)n0 * F_;
  const bf16* A1 = h + (size_t)(b * 2 + 1) * NPAD * F_ + (size_t)n0 * F_;
  const bf16* B0 = W2T + ((size_t)(layer * E_ + e0) * TTPAD + t0) * F_;
  const bf16* B1 = W2T + ((size_t)(layer * E_ + e1) * TTPAD + t0) * F_;
  const int srow = lane & 15, scg8 = (lane >> 4) * 8;
  const int quad = lane >> 4, l15 = lane & 15;
  const int wm = w >> 1, wt = w & 1;   // wave tile: 32(n) x 48(t)

  if (tid < 96) {
    int t = t0 + tid;
    bias_t[tid] = (t < T_)
        ? g0 * be2[(layer * E_ + e0) * T_ + t] + g1 * be2[(layer * E_ + e1) * T_ + t]
        : 0.f;
  }

  f32x4 acc[2][3];
  const f32x4 zero = {0.f, 0.f, 0.f, 0.f};
  #pragma unroll
  for (int i = 0; i < 2; i++)
    #pragma unroll
    for (int jj = 0; jj < 3; jj++) acc[i][jj] = zero;

  for (int kk = 0; kk < 64; ++kk) {    // 2 experts x 32 iters, BK=64
    const bf16* Aj = (kk < 32) ? A0 : A1;
    const bf16* Bj = (kk < 32) ? B0 : B1;
    const int kbase = (kk & 31) * 64;
    #pragma unroll
    for (int hh = 0; hh < 2; hh++) {
      const int fl = kbase + hh * 32 + scg8;
      async_copy16(Aj + (size_t)(w * 16 + srow) * F_ + fl, As2 + hh * 2048 + w * 512);
      async_copy16(Bj + (size_t)(w * 16 + srow) * F_ + fl, Bs2 + hh * 3072 + w * 512);
      if (w < 2)
        async_copy16(Bj + (size_t)((w + 4) * 16 + srow) * F_ + fl,
                     Bs2 + hh * 3072 + (w + 4) * 512);
    }
    __syncthreads();
    #pragma unroll
    for (int hh = 0; hh < 2; hh++) {
      bf16x8 af[2], bfr[3];
      #pragma unroll
      for (int mi = 0; mi < 2; mi++)
        af[mi] = *(const bf16x8*)(As2 + hh * 2048 + (wm * 2 + mi) * 512 + quad * 128 + l15 * 8);
      #pragma unroll
      for (int ni = 0; ni < 3; ni++)
        bfr[ni] = *(const bf16x8*)(Bs2 + hh * 3072 + (wt * 3 + ni) * 512 + quad * 128 + l15 * 8);
      #pragma unroll
      for (int mi = 0; mi < 2; mi++)
        #pragma unroll
        for (int ni = 0; ni < 3; ni++)
          acc[mi][ni] = __builtin_amdgcn_mfma_f32_16x16x32_bf16(af[mi], bfr[ni], acc[mi][ni], 0, 0, 0);
    }
    __syncthreads();
  }

  // ---- fused pack epilogue: residual merge -> out (fp32) + C-tile -> LDS (bf16)
  #pragma unroll
  for (int mi = 0; mi < 2; mi++) {
    #pragma unroll
    for (int ni = 0; ni < 3; ni++) {
      int nloc_b = wm * 32 + mi * 16 + quad * 4;
      int tloc = wt * 48 + ni * 16 + l15;
      int t = t0 + tloc;
      #pragma unroll
      for (int r = 0; r < 4; r++) {
        int nloc = nloc_b + r;
        int n = n0 + nloc;
        float vv = 0.f;
        if (n < N_ && t < T_) {
          size_t q = ((size_t)b * T_ + t) * N_ + n;
          vv = out[q] + acc[mi][ni][r] + bias_t[tloc];
          out[q] = vv;
        }
        S[nloc * CT_STRIDE + tloc] = __float2bfloat16(vv);
      }
    }
  }
  __syncthreads();
  // transpose-store Abuf rows (coalesced 16B segments); pad cols (t>=T) get zeros
  #pragma unroll
  for (int it = 0; it < 3; ++it) {
    int idx = tid + it * 256;          // < 768 = 64 rows * 12 segs
    int row = idx / 12, seg = idx % 12;
    int t = t0 + seg * 8;
    if (t < TPAD)
      *(uint4*)(Abuf + ((size_t)b * NPAD + n0 + row) * TPAD + t) =
          *(const uint4*)(S + row * CT_STRIDE + seg * 8);
  }
}

// ---------------- projection head: fused two-stage MFMA -----------------------------
#define HS_STRIDE 104  // 96 + 8 pad (208B row stride, 16B-aligned; 2-way aliasing free)
__global__ __launch_bounds__(256) void proj_kernel(
    const bf16* __restrict__ Abuf, const bf16* __restrict__ P1T, const float* __restrict__ P1b,
    const bf16* __restrict__ P2T, const float* __restrict__ P2b,
    const float* __restrict__ loss_partial, float* __restrict__ dout) {
  __shared__ __align__(16) bf16 Hs[128 * HS_STRIDE];
  const int tid = threadIdx.x;
  const int w = tid >> 6, lane = tid & 63;
  const int quad = lane >> 4, l15 = lane & 15;
  const int b = blockIdx.y;
  const int m0 = blockIdx.x * 128;

  f32x4 acc1[2][6];
  const f32x4 zero = {0.f, 0.f, 0.f, 0.f};
  #pragma unroll
  for (int i = 0; i < 2; i++)
    #pragma unroll
    for (int j = 0; j < 6; j++) acc1[i][j] = zero;

  const bf16* Arow = Abuf + ((size_t)b * NPAD + m0 + w * 32) * TPAD;
  for (int kk = 0; kk < TPAD / 32; ++kk) {
    bf16x8 af[2], bfr[6];
    #pragma unroll
    for (int mi = 0; mi < 2; mi++)
      af[mi] = *(const bf16x8*)(Arow + (size_t)(mi * 16 + l15) * TPAD + kk * 32 + quad * 8);
    #pragma unroll
    for (int ni = 0; ni < 6; ni++)
      bfr[ni] = *(const bf16x8*)(P1T + (size_t)(ni * 16 + l15) * TPAD + kk * 32 + quad * 8);
    #pragma unroll
    for (int mi = 0; mi < 2; mi++)
      #pragma unroll
      for (int ni = 0; ni < 6; ni++)
        acc1[mi][ni] = __builtin_amdgcn_mfma_f32_16x16x32_bf16(af[mi], bfr[ni], acc1[mi][ni], 0, 0, 0);
  }

  #pragma unroll
  for (int mi = 0; mi < 2; mi++) {
    #pragma unroll
    for (int ni = 0; ni < 6; ni++) {
      float bias = P1b[ni * 16 + l15];
      #pragma unroll
      for (int r = 0; r < 4; r++) {
        float x = acc1[mi][ni][r] + bias;
        float t = 1.f - 2.f / (__expf(2.f * x) + 1.f);
        Hs[(w * 32 + mi * 16 + quad * 4 + r) * HS_STRIDE + ni * 16 + l15] = __float2bfloat16(t);
      }
    }
  }
  __syncthreads();

  #pragma unroll
  for (int half = 0; half < 2; ++half) {
    f32x4 acc2[2][6];
    #pragma unroll
    for (int i = 0; i < 2; i++)
      #pragma unroll
      for (int j = 0; j < 6; j++) acc2[i][j] = zero;

    #pragma unroll
    for (int kk = 0; kk < 3; ++kk) {
      bf16x8 af[2], bfr[6];
      #pragma unroll
      for (int mi = 0; mi < 2; mi++)
        af[mi] = *(const bf16x8*)(Hs + (w * 32 + mi * 16 + l15) * HS_STRIDE + kk * 32 + quad * 8);
      #pragma unroll
      for (int ni = 0; ni < 6; ni++)
        bfr[ni] = *(const bf16x8*)(P2T + (size_t)((half * 6 + ni) * 16 + l15) * P_ + kk * 32 + quad * 8);
      #pragma unroll
      for (int mi = 0; mi < 2; mi++)
        #pragma unroll
        for (int ni = 0; ni < 6; ni++)
          acc2[mi][ni] = __builtin_amdgcn_mfma_f32_16x16x32_bf16(af[mi], bfr[ni], acc2[mi][ni], 0, 0, 0);
    }

    #pragma unroll
    for (int mi = 0; mi < 2; mi++) {
      #pragma unroll
      for (int ni = 0; ni < 6; ni++) {
        int jj = (half * 6 + ni) * 16 + l15;
        float bias = P2b[jj];
        int pout = jj >> 1;
        #pragma unroll
        for (int r = 0; r < 4; r++) {
          int n = m0 + w * 32 + mi * 16 + quad * 4 + r;
          if (n < N_) {
            float s = acc2[mi][ni][r] + bias;
            size_t o = ((size_t)b * P_ + pout) * N_ + n;
            if ((jj & 1) == 0) {
              dout[o] = s;
            } else {
              float sp = (s > 20.f) ? s : log1pf(__expf(s));
              dout[(size_t)B_ * P_ * N_ + 1 + o] = sp + 1e-6f;
            }
          }
        }
      }
    }
  }
  if (b == 0 && blockIdx.x == 0 && tid == 0)
    dout[(size_t)B_ * P_ * N_] = loss_partial[0] + loss_partial[1];
}

// ----------------------------------------------------------------------------------
extern "C" void kernel_launch(void* const* d_in, const int* in_sizes, int n_in,
                              void* d_out, int out_size, void* d_ws, size_t ws_size,
                              hipStream_t stream) {
  const float* x   = (const float*)d_in[0];
  const float* Wg  = (const float*)d_in[11];
  const float* We1 = (const float*)d_in[12];
  const float* be1 = (const float*)d_in[13];
  const float* We2 = (const float*)d_in[14];
  const float* be2 = (const float*)d_in[15];
  const float* P1w = (const float*)d_in[16];
  const float* P1b = (const float*)d_in[17];
  const float* P2w = (const float*)d_in[18];
  const float* P2b = (const float*)d_in[19];

  char* ws = (char*)d_ws;
  size_t off = 0;
  auto alloc = [&](size_t bytes) -> void* {
    void* p = ws + off;
    off += (bytes + 255) & ~(size_t)255;
    return p;
  };
  float* out        = (float*)alloc((size_t)B_ * T_ * N_ * 4);
  bf16*  Abuf       = (bf16*) alloc((size_t)B_ * NPAD * TPAD * 2);
  bf16*  W1T        = (bf16*) alloc((size_t)L_ * E_ * F_ * TPAD * 2);
  bf16*  W2T        = (bf16*) alloc((size_t)L_ * E_ * TTPAD * F_ * 2);
  bf16*  P1T        = (bf16*) alloc((size_t)P_ * TPAD * 2);
  bf16*  P2T        = (bf16*) alloc((size_t)2 * P_ * P_ * 2);
  bf16*  h          = (bf16*) alloc((size_t)B_ * 2 * NPAD * F_ * 2);
  float* logits     = (float*)alloc(B_ * E_ * 4);
  int*   pair_e     = (int*)  alloc(B_ * 2 * 4);
  float* pair_gate  = (float*)alloc(B_ * 2 * 4);
  float* loss_part  = (float*)alloc(2 * 4);
  if (ws_size < off) return;  // workspace too small — bail instead of corrupting

  dim3 tb(32, 8);
  transpose_cast_kernel<<<dim3(11, 64, 8), tb, 0, stream>>>(
      We1, W1T, T_, F_, TPAD, F_, (long long)T_ * F_, (long long)F_ * TPAD);
  transpose_cast_kernel<<<dim3(64, 12, 8), tb, 0, stream>>>(
      We2, W2T, F_, T_, F_, TTPAD, (long long)F_ * T_, (long long)TTPAD * F_);
  transpose_cast_kernel<<<dim3(11, 3, 1), tb, 0, stream>>>(
      P1w, P1T, T_, P_, TPAD, P_, 0, 0);
  transpose_cast_kernel<<<dim3(3, 6, 1), tb, 0, stream>>>(
      P2w, P2T, P_, 2 * P_, P_, 2 * P_, 0, 0);

  revin_kernel<<<dim3(B_, 2), 192, 0, stream>>>(x, out);
  pack_kernel<<<dim3(11, 12, B_), tb, 0, stream>>>(out, Abuf);

  for (int l = 0; l < L_; ++l) {
    gate1_kernel<<<B_, 384, 0, stream>>>(out, Wg, logits, l);
    gate2_kernel<<<1, 64, 0, stream>>>(logits, pair_e, pair_gate, loss_part, l);
    gemm1_kernel<<<dim3(16, 3, 64), 256, 0, stream>>>(Abuf, W1T, be1, pair_e, pair_gate, h, l);
    gemm2_kernel<<<768, 256, 0, stream>>>(h, W2T, be2, pair_e, pair_gate, out, Abuf, l);
  }

  proj_kernel<<<dim3(3, B_), 256, 0, stream>>>(Abuf, P1T, P1b, P2T, P2b, loss_part,
                                               (float*)d_out);
}

// Round 7
// 618.496 us; speedup vs baseline: 1.2899x; 1.2311x over previous
//
#include <hip/hip_runtime.h>
#include <hip/hip_bf16.h>
#include <cstdint>
#include <math.h>

#define B_ 32
#define T_ 336
#define N_ 321
#define L_ 2
#define E_ 4
#define F_ 2048
#define P_ 96
#define TPAD 352   // T padded to multiple of 32 (K of GEMM1 / proj stage1)
#define NPAD 384   // N padded to multiple of 128 (M tiles)
#define TTPAD 384  // T padded (N tiles of GEMM2)

typedef __hip_bfloat16 bf16;
typedef __attribute__((ext_vector_type(8))) __bf16 bf16x8;
typedef __attribute__((ext_vector_type(4))) float f32x4;

__device__ __forceinline__ void async_copy16(const void* g, void* l) {
  __builtin_amdgcn_global_load_lds(
      (__attribute__((address_space(1))) void*)(uintptr_t)g,
      (__attribute__((address_space(3))) void*)(unsigned int)(uintptr_t)l,
      16, 0, 0);
}

// Staging pattern (round-4 proven): lane l reads global row = l>>2, col byte = (l&3)*16
// -> each instruction covers 16 rows x 64B contiguous segments (good coalescing).
// LDS chunk = 16 rows x 32 cols row-major (row*32 + k). Frag reads have ~4-way bank
// aliasing; measured cheaper than 16B-scattered global staging (r5/r6 regression).

// ---------------- transpose + cast fp32 -> bf16 (K-contiguous operand prep) ----------
__global__ void transpose_cast_kernel(const float* __restrict__ src, bf16* __restrict__ dst,
                                      int R, int C, int Rp, int Cp,
                                      long long sStride, long long dStride) {
  __shared__ float tile[32][33];
  const float* s = src + (size_t)blockIdx.z * sStride;
  bf16* d = dst + (size_t)blockIdx.z * dStride;
  int r0 = blockIdx.x * 32, c0 = blockIdx.y * 32;
  int tx = threadIdx.x, ty = threadIdx.y;
  #pragma unroll
  for (int ii = 0; ii < 4; ii++) {
    int rl = ty * 4 + ii;
    int r = r0 + rl, c = c0 + tx;
    tile[rl][tx] = (r < R && c < C) ? s[(size_t)r * C + c] : 0.f;
  }
  __syncthreads();
  #pragma unroll
  for (int ii = 0; ii < 4; ii++) {
    int cl = ty * 4 + ii;
    int cd = c0 + cl, rd = r0 + tx;
    if (cd < Cp && rd < Rp)
      d[(size_t)cd * Rp + rd] = __float2bfloat16(tile[tx][cl]);
  }
}

// ---------------- RevIN + initial pack: x -> out (fp32) and Abuf (bf16, padded) -----
__global__ void revin_kernel(const float* __restrict__ x, float* __restrict__ out,
                             bf16* __restrict__ Abuf) {
  int b = blockIdx.x;
  int n = blockIdx.y * 128 + threadIdx.x;
  if (n >= NPAD) return;
  bf16* arow = Abuf + ((size_t)b * NPAD + n) * TPAD;
  if (n >= N_) {
    for (int t = 0; t < TPAD; t++) arow[t] = __float2bfloat16(0.f);
    return;
  }
  const float* xp = x + ((size_t)b * T_ * N_ + n) * 3;
  float s1 = 0.f, s2 = 0.f;
  for (int t = 0; t < T_; t++) {
    float v = xp[(size_t)t * N_ * 3];
    s1 += v; s2 += v * v;
  }
  float mu = s1 / T_;
  float var = s2 / T_ - mu * mu;
  float inv = 1.f / sqrtf(var + 1e-5f);
  for (int t = 0; t < T_; t++) {
    float v = (xp[(size_t)t * N_ * 3] - mu) * inv;
    out[((size_t)b * T_ + t) * N_ + n] = v;
    arow[t] = __float2bfloat16(v);
  }
  for (int t = T_; t < TPAD; t++) arow[t] = __float2bfloat16(0.f);
}

// ---------------- gating step 1: colmean-sums colsum[b,t] = sum_n out[b,t,n] --------
__global__ void gate1_kernel(const float* __restrict__ out, float* __restrict__ colsum) {
  int b = blockIdx.y;
  int w = threadIdx.x >> 6, lane = threadIdx.x & 63;
  int t = blockIdx.x * 16 + w * 4;
  #pragma unroll
  for (int i = 0; i < 4; i++, t++) {
    const float* p = out + ((size_t)b * T_ + t) * N_;
    float s = 0.f;
    for (int n = lane; n < N_; n += 64) s += p[n];
    #pragma unroll
    for (int off = 32; off; off >>= 1) s += __shfl_down(s, off);
    if (lane == 0) colsum[b * T_ + t] = s;
  }
}

// ---------------- gating step 2: logits + top-2 + softmax + cv^2 loss ---------------
__global__ void gate2_kernel(const float* __restrict__ colsum, const float* __restrict__ Wg,
                             int* __restrict__ pair_e, float* __restrict__ pair_gate,
                             float* __restrict__ loss_partial, int layer) {
  __shared__ float lg[32][4];
  __shared__ float gates[32][4];
  __shared__ float imp[4];
  int tid = threadIdx.x;
  if (tid < 128) {
    int b = tid >> 2, e = tid & 3;
    float s = 0.f;
    for (int t = 0; t < T_; t++)
      s += colsum[b * T_ + t] * Wg[(layer * T_ + t) * E_ + e];
    lg[b][e] = s / (float)N_;
  }
  __syncthreads();
  if (tid < 32) {
    float v[4];
    #pragma unroll
    for (int e = 0; e < 4; e++) v[e] = lg[tid][e];
    int i0 = 0;
    for (int e = 1; e < 4; e++) if (v[e] > v[i0]) i0 = e;     // lowest index wins ties
    int i1 = -1;
    for (int e = 0; e < 4; e++) {
      if (e == i0) continue;
      if (i1 < 0 || v[e] > v[i1]) i1 = e;
    }
    float ex = expf(v[i1] - v[i0]);
    float g0 = 1.f / (1.f + ex);
    float g1 = ex / (1.f + ex);
    pair_e[tid * 2] = i0; pair_e[tid * 2 + 1] = i1;
    pair_gate[tid * 2] = g0; pair_gate[tid * 2 + 1] = g1;
    #pragma unroll
    for (int e = 0; e < 4; e++) gates[tid][e] = 0.f;
    gates[tid][i0] = g0; gates[tid][i1] = g1;
  }
  __syncthreads();
  if (tid < 4) {
    float s = 0.f;
    for (int bb = 0; bb < 32; bb++) s += gates[bb][tid];
    imp[tid] = s;
  }
  __syncthreads();
  if (tid == 0) {
    float m = (imp[0] + imp[1] + imp[2] + imp[3]) * 0.25f;
    float va = 0.f;
    #pragma unroll
    for (int e = 0; e < 4; e++) { float d = imp[e] - m; va += d * d; }
    va *= 0.25f;
    loss_partial[layer] = 0.01f * (va / (m * m + 1e-10f));
  }
}

// ---------------- GEMM1: h[pair] = gate * relu(Abuf[b] @ We1[l,e] + be1) ------------
__global__ __launch_bounds__(256) void gemm1_kernel(
    const bf16* __restrict__ Abuf, const bf16* __restrict__ W1T,
    const float* __restrict__ be1, const int* __restrict__ pair_e,
    const float* __restrict__ pair_gate, bf16* __restrict__ h, int layer) {
  __shared__ __align__(16) bf16 As[128 * 32];
  __shared__ __align__(16) bf16 Bs[128 * 32];
  __shared__ float bias_s[128];

  const int tid = threadIdx.x;
  const int w = tid >> 6, lane = tid & 63;
  const int pair = blockIdx.z;
  const int b = pair >> 1;
  const int e = pair_e[pair];
  const float gate = pair_gate[pair];
  const int m0 = blockIdx.y * 128;  // n-dim
  const int f0 = blockIdx.x * 128;

  const bf16* Ag = Abuf + (size_t)b * NPAD * TPAD + (size_t)m0 * TPAD;
  const bf16* Bg = W1T + ((size_t)(layer * E_ + e) * F_ + f0) * TPAD;
  if (tid < 128) bias_s[tid] = be1[(size_t)(layer * E_ + e) * F_ + f0 + tid];

  f32x4 acc[4][4];
  const f32x4 zero = {0.f, 0.f, 0.f, 0.f};
  #pragma unroll
  for (int i = 0; i < 4; i++)
    #pragma unroll
    for (int j = 0; j < 4; j++) acc[i][j] = zero;

  const int wm = w >> 1, wn = w & 1;
  const int lrow = lane >> 2;          // 64B-coalesced staging (see note)
  const int lkoff = (lane & 3) * 8;
  const int quad = lane >> 4;
  const int l15 = lane & 15;

  for (int kk = 0; kk < TPAD / 32; ++kk) {
    const int k0 = kk * 32;
    #pragma unroll
    for (int i = 0; i < 2; i++) {
      int r = (w * 2 + i) * 16 + lrow;
      async_copy16(Ag + (size_t)r * TPAD + k0 + lkoff, As + (w * 2 + i) * 512);
    }
    #pragma unroll
    for (int i = 0; i < 2; i++) {
      int r = (w * 2 + i) * 16 + lrow;
      async_copy16(Bg + (size_t)r * TPAD + k0 + lkoff, Bs + (w * 2 + i) * 512);
    }
    __syncthreads();
    bf16x8 af[4], bfr[4];
    #pragma unroll
    for (int mi = 0; mi < 4; mi++)
      af[mi] = *(const bf16x8*)(As + (wm * 64 + mi * 16 + l15) * 32 + quad * 8);
    #pragma unroll
    for (int ni = 0; ni < 4; ni++)
      bfr[ni] = *(const bf16x8*)(Bs + (wn * 64 + ni * 16 + l15) * 32 + quad * 8);
    #pragma unroll
    for (int mi = 0; mi < 4; mi++)
      #pragma unroll
      for (int ni = 0; ni < 4; ni++)
        acc[mi][ni] = __builtin_amdgcn_mfma_f32_16x16x32_bf16(af[mi], bfr[ni], acc[mi][ni], 0, 0, 0);
    __syncthreads();
  }

  // epilogue: bias + relu + gate, LDS transpose for coalesced bf16 stores
  bf16* tw0 = As + w * 1024;
  bf16* tw1 = Bs + w * 1024;
  size_t hbase = (size_t)pair * NPAD * F_ + f0 + wn * 64;
  #pragma unroll
  for (int mi = 0; mi < 4; mi++) {
    bf16* tw = (mi & 1) ? tw1 : tw0;
    #pragma unroll
    for (int ni = 0; ni < 4; ni++) {
      float bias = bias_s[wn * 64 + ni * 16 + l15];
      #pragma unroll
      for (int r = 0; r < 4; r++) {
        float v = acc[mi][ni][r] + bias;
        v = fmaxf(v, 0.f) * gate;
        tw[(quad * 4 + r) * 64 + ni * 16 + l15] = __float2bfloat16(v);
      }
    }
    int row = lane >> 2;            // 0..15
    int fpart = (lane & 3) * 16;    // 0,16,32,48
    int ng = m0 + wm * 64 + mi * 16 + row;
    const uint4* sp = (const uint4*)(tw + row * 64 + fpart);
    uint4 d0 = sp[0];
    uint4 d1 = sp[1];
    uint4* dp = (uint4*)(h + hbase + (size_t)ng * F_ + fpart);
    dp[0] = d0; dp[1] = d1;
  }
}

// ---------------- GEMM2+pack fused: both experts per block, K=4096 ------------------
// out[b,t,n] += h[b*2+0] @ We2[e0] + h[b*2+1] @ We2[e1] + g0*be2[e0] + g1*be2[e1]
// and Abuf[b,n,t] = bf16(out) for the next layer / proj.
// Tile 64(n) x 96(t), BK=64. XCD swizzle: the 4 t-tiles of a (b,n)-group land on the
// SAME XCD (ids spaced by 8 under round-robin dispatch) -> shared A-slab in one L2.
#define CT_STRIDE 104
__global__ __launch_bounds__(256) void gemm2_kernel(
    const bf16* __restrict__ h, const bf16* __restrict__ W2T,
    const float* __restrict__ be2, const int* __restrict__ pair_e,
    const float* __restrict__ pair_gate, float* __restrict__ out,
    bf16* __restrict__ Abuf, int layer) {
  // S: loop = As2(2 x 4chunks) + Bs2(2 x 6chunks) = 10240 elems (20KB);
  //    epilogue reuses first 64*CT_STRIDE = 6656 elems as bf16 C-tile.
  __shared__ __align__(16) bf16 S[10240];
  __shared__ float bias_t[96];
  bf16* As2 = S;               // [hh*2048 + chunk*512 + row*32 + k]
  bf16* Bs2 = S + 4096;        // [hh*3072 + chunk*512 + row*32 + k]

  const int tid = threadIdx.x;
  const int w = tid >> 6, lane = tid & 63;
  const int id = blockIdx.x;           // 0..767
  const int u = id & 7;                // XCD (round-robin heuristic)
  const int v = id >> 3;               // 0..95
  const int tt = v & 3;
  const int pn = u + 8 * (v >> 2);     // 0..191
  const int b = pn / 6, nt = pn % 6;
  const int n0 = nt * 64, t0 = tt * 96;

  const int e0 = pair_e[b * 2], e1 = pair_e[b * 2 + 1];
  const float g0 = pair_gate[b * 2], g1 = pair_gate[b * 2 + 1];
  const bf16* A0 = h + (size_t)(b * 2) * NPAD * F_ + (size_t)n0 * F_;
  const bf16* A1 = h + (size_t)(b * 2 + 1) * NPAD * F_ + (size_t)n0 * F_;
  const bf16* B0 = W2T + ((size_t)(layer * E_ + e0) * TTPAD + t0) * F_;
  const bf16* B1 = W2T + ((size_t)(layer * E_ + e1) * TTPAD + t0) * F_;
  const int lrow = lane >> 2, lkoff = (lane & 3) * 8;   // 64B-coalesced staging
  const int quad = lane >> 4, l15 = lane & 15;
  const int wm = w >> 1, wt = w & 1;   // wave tile: 32(n) x 48(t)

  if (tid < 96) {
    int t = t0 + tid;
    bias_t[tid] = (t < T_)
        ? g0 * be2[(layer * E_ + e0) * T_ + t] + g1 * be2[(layer * E_ + e1) * T_ + t]
        : 0.f;
  }

  f32x4 acc[2][3];
  const f32x4 zero = {0.f, 0.f, 0.f, 0.f};
  #pragma unroll
  for (int i = 0; i < 2; i++)
    #pragma unroll
    for (int jj = 0; jj < 3; jj++) acc[i][jj] = zero;

  for (int kk = 0; kk < 64; ++kk) {    // 2 experts x 32 iters, BK=64
    const bf16* Aj = (kk < 32) ? A0 : A1;
    const bf16* Bj = (kk < 32) ? B0 : B1;
    const int kbase = (kk & 31) * 64;
    #pragma unroll
    for (int hh = 0; hh < 2; hh++) {
      const int fl = kbase + hh * 32 + lkoff;
      async_copy16(Aj + (size_t)(w * 16 + lrow) * F_ + fl, As2 + hh * 2048 + w * 512);
      async_copy16(Bj + (size_t)(w * 16 + lrow) * F_ + fl, Bs2 + hh * 3072 + w * 512);
      if (w < 2)
        async_copy16(Bj + (size_t)((w + 4) * 16 + lrow) * F_ + fl,
                     Bs2 + hh * 3072 + (w + 4) * 512);
    }
    __syncthreads();
    #pragma unroll
    for (int hh = 0; hh < 2; hh++) {
      bf16x8 af[2], bfr[3];
      #pragma unroll
      for (int mi = 0; mi < 2; mi++)
        af[mi] = *(const bf16x8*)(As2 + hh * 2048 + (wm * 32 + mi * 16 + l15) * 32 + quad * 8);
      #pragma unroll
      for (int ni = 0; ni < 3; ni++)
        bfr[ni] = *(const bf16x8*)(Bs2 + hh * 3072 + (wt * 48 + ni * 16 + l15) * 32 + quad * 8);
      #pragma unroll
      for (int mi = 0; mi < 2; mi++)
        #pragma unroll
        for (int ni = 0; ni < 3; ni++)
          acc[mi][ni] = __builtin_amdgcn_mfma_f32_16x16x32_bf16(af[mi], bfr[ni], acc[mi][ni], 0, 0, 0);
    }
    __syncthreads();
  }

  // ---- fused pack epilogue: residual merge -> out (fp32) + C-tile -> LDS (bf16)
  #pragma unroll
  for (int mi = 0; mi < 2; mi++) {
    #pragma unroll
    for (int ni = 0; ni < 3; ni++) {
      int nloc_b = wm * 32 + mi * 16 + quad * 4;
      int tloc = wt * 48 + ni * 16 + l15;
      int t = t0 + tloc;
      #pragma unroll
      for (int r = 0; r < 4; r++) {
        int nloc = nloc_b + r;
        int n = n0 + nloc;
        float vv = 0.f;
        if (n < N_ && t < T_) {
          size_t q = ((size_t)b * T_ + t) * N_ + n;
          vv = out[q] + acc[mi][ni][r] + bias_t[tloc];
          out[q] = vv;
        }
        S[nloc * CT_STRIDE + tloc] = __float2bfloat16(vv);
      }
    }
  }
  __syncthreads();
  // transpose-store Abuf rows (coalesced 16B segments); pad cols (t>=T) get zeros
  #pragma unroll
  for (int it = 0; it < 3; ++it) {
    int idx = tid + it * 256;          // < 768 = 64 rows * 12 segs
    int row = idx / 12, seg = idx % 12;
    int t = t0 + seg * 8;
    if (t < TPAD)
      *(uint4*)(Abuf + ((size_t)b * NPAD + n0 + row) * TPAD + t) =
          *(const uint4*)(S + row * CT_STRIDE + seg * 8);
  }
}

// ---------------- projection head: fused two-stage MFMA -----------------------------
#define HS_STRIDE 104  // 96 + 8 pad (208B row stride, 16B-aligned; 2-way aliasing free)
__global__ __launch_bounds__(256) void proj_kernel(
    const bf16* __restrict__ Abuf, const bf16* __restrict__ P1T, const float* __restrict__ P1b,
    const bf16* __restrict__ P2T, const float* __restrict__ P2b,
    const float* __restrict__ loss_partial, float* __restrict__ dout) {
  __shared__ __align__(16) bf16 Hs[128 * HS_STRIDE];
  const int tid = threadIdx.x;
  const int w = tid >> 6, lane = tid & 63;
  const int quad = lane >> 4, l15 = lane & 15;
  const int b = blockIdx.y;
  const int m0 = blockIdx.x * 128;

  f32x4 acc1[2][6];
  const f32x4 zero = {0.f, 0.f, 0.f, 0.f};
  #pragma unroll
  for (int i = 0; i < 2; i++)
    #pragma unroll
    for (int j = 0; j < 6; j++) acc1[i][j] = zero;

  const bf16* Arow = Abuf + ((size_t)b * NPAD + m0 + w * 32) * TPAD;
  for (int kk = 0; kk < TPAD / 32; ++kk) {
    bf16x8 af[2], bfr[6];
    #pragma unroll
    for (int mi = 0; mi < 2; mi++)
      af[mi] = *(const bf16x8*)(Arow + (size_t)(mi * 16 + l15) * TPAD + kk * 32 + quad * 8);
    #pragma unroll
    for (int ni = 0; ni < 6; ni++)
      bfr[ni] = *(const bf16x8*)(P1T + (size_t)(ni * 16 + l15) * TPAD + kk * 32 + quad * 8);
    #pragma unroll
    for (int mi = 0; mi < 2; mi++)
      #pragma unroll
      for (int ni = 0; ni < 6; ni++)
        acc1[mi][ni] = __builtin_amdgcn_mfma_f32_16x16x32_bf16(af[mi], bfr[ni], acc1[mi][ni], 0, 0, 0);
  }

  #pragma unroll
  for (int mi = 0; mi < 2; mi++) {
    #pragma unroll
    for (int ni = 0; ni < 6; ni++) {
      float bias = P1b[ni * 16 + l15];
      #pragma unroll
      for (int r = 0; r < 4; r++) {
        float x = acc1[mi][ni][r] + bias;
        float t = 1.f - 2.f / (__expf(2.f * x) + 1.f);
        Hs[(w * 32 + mi * 16 + quad * 4 + r) * HS_STRIDE + ni * 16 + l15] = __float2bfloat16(t);
      }
    }
  }
  __syncthreads();

  #pragma unroll
  for (int half = 0; half < 2; ++half) {
    f32x4 acc2[2][6];
    #pragma unroll
    for (int i = 0; i < 2; i++)
      #pragma unroll
      for (int j = 0; j < 6; j++) acc2[i][j] = zero;

    #pragma unroll
    for (int kk = 0; kk < 3; ++kk) {
      bf16x8 af[2], bfr[6];
      #pragma unroll
      for (int mi = 0; mi < 2; mi++)
        af[mi] = *(const bf16x8*)(Hs + (w * 32 + mi * 16 + l15) * HS_STRIDE + kk * 32 + quad * 8);
      #pragma unroll
      for (int ni = 0; ni < 6; ni++)
        bfr[ni] = *(const bf16x8*)(P2T + (size_t)((half * 6 + ni) * 16 + l15) * P_ + kk * 32 + quad * 8);
      #pragma unroll
      for (int mi = 0; mi < 2; mi++)
        #pragma unroll
        for (int ni = 0; ni < 6; ni++)
          acc2[mi][ni] = __builtin_amdgcn_mfma_f32_16x16x32_bf16(af[mi], bfr[ni], acc2[mi][ni], 0, 0, 0);
    }

    #pragma unroll
    for (int mi = 0; mi < 2; mi++) {
      #pragma unroll
      for (int ni = 0; ni < 6; ni++) {
        int jj = (half * 6 + ni) * 16 + l15;
        float bias = P2b[jj];
        int pout = jj >> 1;
        #pragma unroll
        for (int r = 0; r < 4; r++) {
          int n = m0 + w * 32 + mi * 16 + quad * 4 + r;
          if (n < N_) {
            float s = acc2[mi][ni][r] + bias;
            size_t o = ((size_t)b * P_ + pout) * N_ + n;
            if ((jj & 1) == 0) {
              dout[o] = s;
            } else {
              float sp = (s > 20.f) ? s : log1pf(__expf(s));
              dout[(size_t)B_ * P_ * N_ + 1 + o] = sp + 1e-6f;
            }
          }
        }
      }
    }
  }
  if (b == 0 && blockIdx.x == 0 && tid == 0)
    dout[(size_t)B_ * P_ * N_] = loss_partial[0] + loss_partial[1];
}

// ----------------------------------------------------------------------------------
extern "C" void kernel_launch(void* const* d_in, const int* in_sizes, int n_in,
                              void* d_out, int out_size, void* d_ws, size_t ws_size,
                              hipStream_t stream) {
  const float* x   = (const float*)d_in[0];
  const float* Wg  = (const float*)d_in[11];
  const float* We1 = (const float*)d_in[12];
  const float* be1 = (const float*)d_in[13];
  const float* We2 = (const float*)d_in[14];
  const float* be2 = (const float*)d_in[15];
  const float* P1w = (const float*)d_in[16];
  const float* P1b = (const float*)d_in[17];
  const float* P2w = (const float*)d_in[18];
  const float* P2b = (const float*)d_in[19];

  char* ws = (char*)d_ws;
  size_t off = 0;
  auto alloc = [&](size_t bytes) -> void* {
    void* p = ws + off;
    off += (bytes + 255) & ~(size_t)255;
    return p;
  };
  float* out        = (float*)alloc((size_t)B_ * T_ * N_ * 4);
  bf16*  Abuf       = (bf16*) alloc((size_t)B_ * NPAD * TPAD * 2);
  bf16*  W1T        = (bf16*) alloc((size_t)L_ * E_ * F_ * TPAD * 2);
  bf16*  W2T        = (bf16*) alloc((size_t)L_ * E_ * TTPAD * F_ * 2);
  bf16*  P1T        = (bf16*) alloc((size_t)P_ * TPAD * 2);
  bf16*  P2T        = (bf16*) alloc((size_t)2 * P_ * P_ * 2);
  bf16*  h          = (bf16*) alloc((size_t)B_ * 2 * NPAD * F_ * 2);
  float* colsum     = (float*)alloc((size_t)B_ * T_ * 4);
  int*   pair_e     = (int*)  alloc(B_ * 2 * 4);
  float* pair_gate  = (float*)alloc(B_ * 2 * 4);
  float* loss_part  = (float*)alloc(2 * 4);
  if (ws_size < off) return;  // workspace too small — bail instead of corrupting

  dim3 tb(32, 8);
  transpose_cast_kernel<<<dim3(11, 64, 8), tb, 0, stream>>>(
      We1, W1T, T_, F_, TPAD, F_, (long long)T_ * F_, (long long)F_ * TPAD);
  transpose_cast_kernel<<<dim3(64, 12, 8), tb, 0, stream>>>(
      We2, W2T, F_, T_, F_, TTPAD, (long long)F_ * T_, (long long)TTPAD * F_);
  transpose_cast_kernel<<<dim3(11, 3, 1), tb, 0, stream>>>(
      P1w, P1T, T_, P_, TPAD, P_, 0, 0);
  transpose_cast_kernel<<<dim3(3, 6, 1), tb, 0, stream>>>(
      P2w, P2T, P_, 2 * P_, P_, 2 * P_, 0, 0);

  revin_kernel<<<dim3(B_, 3), 128, 0, stream>>>(x, out, Abuf);

  for (int l = 0; l < L_; ++l) {
    gate1_kernel<<<dim3(21, B_), 256, 0, stream>>>(out, colsum);
    gate2_kernel<<<1, 128, 0, stream>>>(colsum, Wg, pair_e, pair_gate, loss_part, l);
    gemm1_kernel<<<dim3(16, 3, 64), 256, 0, stream>>>(Abuf, W1T, be1, pair_e, pair_gate, h, l);
    gemm2_kernel<<<768, 256, 0, stream>>>(h, W2T, be2, pair_e, pair_gate, out, Abuf, l);
  }

  proj_kernel<<<dim3(3, B_), 256, 0, stream>>>(Abuf, P1T, P1b, P2T, P2b, loss_part,
                                               (float*)d_out);
}

// Round 8
// 599.676 us; speedup vs baseline: 1.3304x; 1.0314x over previous
//
#include <hip/hip_runtime.h>
#include <hip/hip_bf16.h>
#include <cstdint>
#include <math.h>

#define B_ 32
#define T_ 336
#define N_ 321
#define L_ 2
#define E_ 4
#define F_ 2048
#define P_ 96
#define TPAD 352   // T padded to multiple of 32 (K of GEMM1 / proj stage1)
#define NPAD 384   // N padded to multiple of 128 (M tiles)

typedef __hip_bfloat16 bf16;
typedef __attribute__((ext_vector_type(8))) __bf16 bf16x8;
typedef __attribute__((ext_vector_type(4))) float f32x4;

// h blocked layout: h[pair][nb][kg][row64][8]  (kg = f/8, j = f%8)
//   kg stride 512 els, nb stride 131072 els, pair stride 786432 els.
// W2 blocked layout: W2B[le][tb][kg][row96][8]
//   kg stride 768 els, tb stride 196608 els, le stride 786432 els.
// gemm2 staging is fully linear per chunk -> contiguous HBM streams.

__device__ __forceinline__ void async_copy16(const void* g, void* l) {
  __builtin_amdgcn_global_load_lds(
      (__attribute__((address_space(1))) void*)(uintptr_t)g,
      (__attribute__((address_space(3))) void*)(unsigned int)(uintptr_t)l,
      16, 0, 0);
}

// ---------------- transpose + cast fp32 -> bf16 (K-contiguous operand prep) ----------
__global__ void transpose_cast_kernel(const float* __restrict__ src, bf16* __restrict__ dst,
                                      int R, int C, int Rp, int Cp,
                                      long long sStride, long long dStride) {
  __shared__ float tile[32][33];
  const float* s = src + (size_t)blockIdx.z * sStride;
  bf16* d = dst + (size_t)blockIdx.z * dStride;
  int r0 = blockIdx.x * 32, c0 = blockIdx.y * 32;
  int tx = threadIdx.x, ty = threadIdx.y;
  #pragma unroll
  for (int ii = 0; ii < 4; ii++) {
    int rl = ty * 4 + ii;
    int r = r0 + rl, c = c0 + tx;
    tile[rl][tx] = (r < R && c < C) ? s[(size_t)r * C + c] : 0.f;
  }
  __syncthreads();
  #pragma unroll
  for (int ii = 0; ii < 4; ii++) {
    int cl = ty * 4 + ii;
    int cd = c0 + cl, rd = r0 + tx;
    if (cd < Cp && rd < Rp)
      d[(size_t)cd * Rp + rd] = __float2bfloat16(tile[tx][cl]);
  }
}

// ---------------- We2 -> k-blocked W2B ---------------------------------------------
// grid (F/32, 4, L*E); dst[le][tb][kg][row96][8] = We2[le][f=kg*8+j][t=tb*96+row]
__global__ void repack_w2_kernel(const float* __restrict__ src, bf16* __restrict__ dst) {
  __shared__ float tile[32][96];
  int le = blockIdx.z, tb = blockIdx.y, f0 = blockIdx.x * 32;
  int tid = threadIdx.x;
  const float* s = src + (size_t)le * F_ * T_;
  for (int idx = tid; idx < 32 * 96; idx += 256) {
    int ff = idx / 96, tt = idx % 96;
    int t = tb * 96 + tt;
    tile[ff][tt] = (t < T_) ? s[(size_t)(f0 + ff) * T_ + t] : 0.f;
  }
  __syncthreads();
  bf16* d = dst + ((size_t)le * 4 + tb) * 196608 + (size_t)(f0 >> 3) * 768;
  for (int s2 = tid; s2 < 384; s2 += 256) {
    int kgl = s2 / 96, row = s2 % 96;
    bf16 v[8];
    #pragma unroll
    for (int j = 0; j < 8; j++) v[j] = __float2bfloat16(tile[kgl * 8 + j][row]);
    *(uint4*)(d + (size_t)kgl * 768 + row * 8) = *(const uint4*)v;
  }
}

// ---------------- RevIN + initial pack: x -> out (fp32) and Abuf (bf16, padded) -----
__global__ void revin_kernel(const float* __restrict__ x, float* __restrict__ out,
                             bf16* __restrict__ Abuf) {
  int b = blockIdx.x;
  int n = blockIdx.y * 128 + threadIdx.x;
  if (n >= NPAD) return;
  bf16* arow = Abuf + ((size_t)b * NPAD + n) * TPAD;
  if (n >= N_) {
    for (int t = 0; t < TPAD; t++) arow[t] = __float2bfloat16(0.f);
    return;
  }
  const float* xp = x + ((size_t)b * T_ * N_ + n) * 3;
  float s1 = 0.f, s2 = 0.f;
  for (int t = 0; t < T_; t++) {
    float v = xp[(size_t)t * N_ * 3];
    s1 += v; s2 += v * v;
  }
  float mu = s1 / T_;
  float var = s2 / T_ - mu * mu;
  float inv = 1.f / sqrtf(var + 1e-5f);
  for (int t = 0; t < T_; t++) {
    float v = (xp[(size_t)t * N_ * 3] - mu) * inv;
    out[((size_t)b * T_ + t) * N_ + n] = v;
    arow[t] = __float2bfloat16(v);
  }
  for (int t = T_; t < TPAD; t++) arow[t] = __float2bfloat16(0.f);
}

// ---------------- gating step 1: colsum[b,t] = sum_n out[b,t,n] ---------------------
__global__ void gate1_kernel(const float* __restrict__ out, float* __restrict__ colsum) {
  int b = blockIdx.y;
  int w = threadIdx.x >> 6, lane = threadIdx.x & 63;
  int t = blockIdx.x * 16 + w * 4;
  #pragma unroll
  for (int i = 0; i < 4; i++, t++) {
    const float* p = out + ((size_t)b * T_ + t) * N_;
    float s = 0.f;
    for (int n = lane; n < N_; n += 64) s += p[n];
    #pragma unroll
    for (int off = 32; off; off >>= 1) s += __shfl_down(s, off);
    if (lane == 0) colsum[b * T_ + t] = s;
  }
}

// ---------------- gating step 2: logits + top-2 + softmax + cv^2 loss ---------------
__global__ void gate2_kernel(const float* __restrict__ colsum, const float* __restrict__ Wg,
                             int* __restrict__ pair_e, float* __restrict__ pair_gate,
                             float* __restrict__ loss_partial, int layer) {
  __shared__ float lg[32][4];
  __shared__ float gates[32][4];
  __shared__ float imp[4];
  int tid = threadIdx.x;
  if (tid < 128) {
    int b = tid >> 2, e = tid & 3;
    float s = 0.f;
    for (int t = 0; t < T_; t++)
      s += colsum[b * T_ + t] * Wg[(layer * T_ + t) * E_ + e];
    lg[b][e] = s / (float)N_;
  }
  __syncthreads();
  if (tid < 32) {
    float v[4];
    #pragma unroll
    for (int e = 0; e < 4; e++) v[e] = lg[tid][e];
    int i0 = 0;
    for (int e = 1; e < 4; e++) if (v[e] > v[i0]) i0 = e;     // lowest index wins ties
    int i1 = -1;
    for (int e = 0; e < 4; e++) {
      if (e == i0) continue;
      if (i1 < 0 || v[e] > v[i1]) i1 = e;
    }
    float ex = expf(v[i1] - v[i0]);
    float g0 = 1.f / (1.f + ex);
    float g1 = ex / (1.f + ex);
    pair_e[tid * 2] = i0; pair_e[tid * 2 + 1] = i1;
    pair_gate[tid * 2] = g0; pair_gate[tid * 2 + 1] = g1;
    #pragma unroll
    for (int e = 0; e < 4; e++) gates[tid][e] = 0.f;
    gates[tid][i0] = g0; gates[tid][i1] = g1;
  }
  __syncthreads();
  if (tid < 4) {
    float s = 0.f;
    for (int bb = 0; bb < 32; bb++) s += gates[bb][tid];
    imp[tid] = s;
  }
  __syncthreads();
  if (tid == 0) {
    float m = (imp[0] + imp[1] + imp[2] + imp[3]) * 0.25f;
    float va = 0.f;
    #pragma unroll
    for (int e = 0; e < 4; e++) { float d = imp[e] - m; va += d * d; }
    va *= 0.25f;
    loss_partial[layer] = 0.01f * (va / (m * m + 1e-10f));
  }
}

// ---------------- GEMM1: h[pair] = gate * relu(Abuf[b] @ We1[l,e] + be1) ------------
// h written in blocked layout (see top).
__global__ __launch_bounds__(256) void gemm1_kernel(
    const bf16* __restrict__ Abuf, const bf16* __restrict__ W1T,
    const float* __restrict__ be1, const int* __restrict__ pair_e,
    const float* __restrict__ pair_gate, bf16* __restrict__ h, int layer) {
  __shared__ __align__(16) bf16 As[128 * 32];
  __shared__ __align__(16) bf16 Bs[128 * 32];
  __shared__ float bias_s[128];

  const int tid = threadIdx.x;
  const int w = tid >> 6, lane = tid & 63;
  const int pair = blockIdx.z;
  const int b = pair >> 1;
  const int e = pair_e[pair];
  const float gate = pair_gate[pair];
  const int m0 = blockIdx.y * 128;  // n-dim
  const int f0 = blockIdx.x * 128;

  const bf16* Ag = Abuf + (size_t)b * NPAD * TPAD + (size_t)m0 * TPAD;
  const bf16* Bg = W1T + ((size_t)(layer * E_ + e) * F_ + f0) * TPAD;
  if (tid < 128) bias_s[tid] = be1[(size_t)(layer * E_ + e) * F_ + f0 + tid];

  f32x4 acc[4][4];
  const f32x4 zero = {0.f, 0.f, 0.f, 0.f};
  #pragma unroll
  for (int i = 0; i < 4; i++)
    #pragma unroll
    for (int j = 0; j < 4; j++) acc[i][j] = zero;

  const int wm = w >> 1, wn = w & 1;
  const int lrow = lane >> 2;          // 64B-coalesced staging
  const int lkoff = (lane & 3) * 8;
  const int quad = lane >> 4;
  const int l15 = lane & 15;

  for (int kk = 0; kk < TPAD / 32; ++kk) {
    const int k0 = kk * 32;
    #pragma unroll
    for (int i = 0; i < 2; i++) {
      int r = (w * 2 + i) * 16 + lrow;
      async_copy16(Ag + (size_t)r * TPAD + k0 + lkoff, As + (w * 2 + i) * 512);
    }
    #pragma unroll
    for (int i = 0; i < 2; i++) {
      int r = (w * 2 + i) * 16 + lrow;
      async_copy16(Bg + (size_t)r * TPAD + k0 + lkoff, Bs + (w * 2 + i) * 512);
    }
    __syncthreads();
    bf16x8 af[4], bfr[4];
    #pragma unroll
    for (int mi = 0; mi < 4; mi++)
      af[mi] = *(const bf16x8*)(As + (wm * 64 + mi * 16 + l15) * 32 + quad * 8);
    #pragma unroll
    for (int ni = 0; ni < 4; ni++)
      bfr[ni] = *(const bf16x8*)(Bs + (wn * 64 + ni * 16 + l15) * 32 + quad * 8);
    #pragma unroll
    for (int mi = 0; mi < 4; mi++)
      #pragma unroll
      for (int ni = 0; ni < 4; ni++)
        acc[mi][ni] = __builtin_amdgcn_mfma_f32_16x16x32_bf16(af[mi], bfr[ni], acc[mi][ni], 0, 0, 0);
    __syncthreads();
  }

  // epilogue: bias + relu + gate, LDS transpose, then blocked-layout h stores
  bf16* tw0 = As + w * 1024;
  bf16* tw1 = Bs + w * 1024;
  // this wave's rows live in nb = m0/64 + wm, rows mi*16 + (lane>>2)
  size_t hb = (size_t)pair * 786432 + (size_t)((m0 >> 6) + wm) * 131072;
  const int kgbase = (f0 >> 3) + wn * 8 + (lane & 3) * 2;
  #pragma unroll
  for (int mi = 0; mi < 4; mi++) {
    bf16* tw = (mi & 1) ? tw1 : tw0;
    #pragma unroll
    for (int ni = 0; ni < 4; ni++) {
      float bias = bias_s[wn * 64 + ni * 16 + l15];
      #pragma unroll
      for (int r = 0; r < 4; r++) {
        float v = acc[mi][ni][r] + bias;
        v = fmaxf(v, 0.f) * gate;
        tw[(quad * 4 + r) * 64 + ni * 16 + l15] = __float2bfloat16(v);
      }
    }
    int row = lane >> 2;            // 0..15
    int fpart = (lane & 3) * 16;    // 0,16,32,48
    const uint4* sp = (const uint4*)(tw + row * 64 + fpart);
    uint4 d0 = sp[0];
    uint4 d1 = sp[1];
    bf16* dp = h + hb + (size_t)kgbase * 512 + (mi * 16 + row) * 8;
    *(uint4*)dp = d0;
    *(uint4*)(dp + 512) = d1;
  }
}

// ---------------- GEMM2+pack fused: both experts per block, K=4096 ------------------
// out[b,t,n] += h@We2 (both experts) + gated be2; Abuf[b,n,t] = bf16(out).
// Tile 64(n) x 96(t), BK=64; A/B staged as LINEAR contiguous chunks (blocked layouts).
// XCD swizzle keeps the 4 t-tiles of a (b,n)-group on one XCD.
#define CT_STRIDE 104
__global__ __launch_bounds__(256) void gemm2_kernel(
    const bf16* __restrict__ h, const bf16* __restrict__ W2B,
    const float* __restrict__ be2, const int* __restrict__ pair_e,
    const float* __restrict__ pair_gate, float* __restrict__ out,
    bf16* __restrict__ Abuf, int layer) {
  // S: loop = As2 (4096 els, 8KB) + Bs2 (6144 els, 12KB);
  //    epilogue reuses first 64*CT_STRIDE = 6656 els as bf16 C-tile.
  __shared__ __align__(16) bf16 S[10240];
  __shared__ float bias_t[96];
  bf16* As2 = S;           // linear [kg(8)][row64][8]
  bf16* Bs2 = S + 4096;    // linear [kg(8)][row96][8]

  const int tid = threadIdx.x;
  const int w = tid >> 6, lane = tid & 63;
  const int id = blockIdx.x;           // 0..767
  const int u = id & 7;                // XCD (round-robin heuristic)
  const int v = id >> 3;               // 0..95
  const int tt = v & 3;
  const int pn = u + 8 * (v >> 2);     // 0..191
  const int b = pn / 6, nt = pn % 6;
  const int n0 = nt * 64, t0 = tt * 96;

  const int e0 = pair_e[b * 2], e1 = pair_e[b * 2 + 1];
  const float g0 = pair_gate[b * 2], g1 = pair_gate[b * 2 + 1];
  const bf16* Agb0 = h + ((size_t)(b * 2) * 6 + nt) * 131072;
  const bf16* Agb1 = h + ((size_t)(b * 2 + 1) * 6 + nt) * 131072;
  const bf16* Bgb0 = W2B + ((size_t)(layer * E_ + e0) * 4 + tt) * 196608;
  const bf16* Bgb1 = W2B + ((size_t)(layer * E_ + e1) * 4 + tt) * 196608;
  const int quad = lane >> 4, l15 = lane & 15;
  const int wm = w >> 1, wt = w & 1;   // wave tile: 32(n) x 48(t)

  if (tid < 96) {
    int t = t0 + tid;
    bias_t[tid] = (t < T_)
        ? g0 * be2[(layer * E_ + e0) * T_ + t] + g1 * be2[(layer * E_ + e1) * T_ + t]
        : 0.f;
  }

  f32x4 acc[2][3];
  const f32x4 zero = {0.f, 0.f, 0.f, 0.f};
  #pragma unroll
  for (int i = 0; i < 2; i++)
    #pragma unroll
    for (int jj = 0; jj < 3; jj++) acc[i][jj] = zero;

  for (int kk = 0; kk < 64; ++kk) {    // 2 experts x 32 iters, BK=64
    const bf16* Aj = ((kk < 32) ? Agb0 : Agb1) + (size_t)(kk & 31) * 4096;
    const bf16* Bj = ((kk < 32) ? Bgb0 : Bgb1) + (size_t)(kk & 31) * 6144;
    #pragma unroll
    for (int i = 0; i < 2; i++)
      async_copy16(Aj + (w * 2 + i) * 512 + lane * 8, As2 + (w * 2 + i) * 512);
    #pragma unroll
    for (int i = 0; i < 3; i++)
      async_copy16(Bj + (w * 3 + i) * 512 + lane * 8, Bs2 + (w * 3 + i) * 512);
    __syncthreads();
    #pragma unroll
    for (int w32 = 0; w32 < 2; w32++) {
      const int kg = w32 * 4 + quad;
      bf16x8 af[2], bfr[3];
      #pragma unroll
      for (int mi = 0; mi < 2; mi++)
        af[mi] = *(const bf16x8*)(As2 + kg * 512 + (wm * 32 + mi * 16 + l15) * 8);
      #pragma unroll
      for (int ni = 0; ni < 3; ni++)
        bfr[ni] = *(const bf16x8*)(Bs2 + kg * 768 + (wt * 48 + ni * 16 + l15) * 8);
      #pragma unroll
      for (int mi = 0; mi < 2; mi++)
        #pragma unroll
        for (int ni = 0; ni < 3; ni++)
          acc[mi][ni] = __builtin_amdgcn_mfma_f32_16x16x32_bf16(af[mi], bfr[ni], acc[mi][ni], 0, 0, 0);
    }
    __syncthreads();
  }

  // ---- fused pack epilogue: residual merge -> out (fp32) + C-tile -> LDS (bf16)
  #pragma unroll
  for (int mi = 0; mi < 2; mi++) {
    #pragma unroll
    for (int ni = 0; ni < 3; ni++) {
      int nloc_b = wm * 32 + mi * 16 + quad * 4;
      int tloc = wt * 48 + ni * 16 + l15;
      int t = t0 + tloc;
      #pragma unroll
      for (int r = 0; r < 4; r++) {
        int nloc = nloc_b + r;
        int n = n0 + nloc;
        float vv = 0.f;
        if (n < N_ && t < T_) {
          size_t q = ((size_t)b * T_ + t) * N_ + n;
          vv = out[q] + acc[mi][ni][r] + bias_t[tloc];
          out[q] = vv;
        }
        S[nloc * CT_STRIDE + tloc] = __float2bfloat16(vv);
      }
    }
  }
  __syncthreads();
  // transpose-store Abuf rows (coalesced 16B segments); pad cols (t>=T) get zeros
  #pragma unroll
  for (int it = 0; it < 3; ++it) {
    int idx = tid + it * 256;          // < 768 = 64 rows * 12 segs
    int row = idx / 12, seg = idx % 12;
    int t = t0 + seg * 8;
    if (t < TPAD)
      *(uint4*)(Abuf + ((size_t)b * NPAD + n0 + row) * TPAD + t) =
          *(const uint4*)(S + row * CT_STRIDE + seg * 8);
  }
}

// ---------------- projection head: fused two-stage MFMA -----------------------------
#define HS_STRIDE 104  // 96 + 8 pad (208B row stride, 16B-aligned)
__global__ __launch_bounds__(256) void proj_kernel(
    const bf16* __restrict__ Abuf, const bf16* __restrict__ P1T, const float* __restrict__ P1b,
    const bf16* __restrict__ P2T, const float* __restrict__ P2b,
    const float* __restrict__ loss_partial, float* __restrict__ dout) {
  __shared__ __align__(16) bf16 Hs[128 * HS_STRIDE];
  const int tid = threadIdx.x;
  const int w = tid >> 6, lane = tid & 63;
  const int quad = lane >> 4, l15 = lane & 15;
  const int b = blockIdx.y;
  const int m0 = blockIdx.x * 128;

  f32x4 acc1[2][6];
  const f32x4 zero = {0.f, 0.f, 0.f, 0.f};
  #pragma unroll
  for (int i = 0; i < 2; i++)
    #pragma unroll
    for (int j = 0; j < 6; j++) acc1[i][j] = zero;

  const bf16* Arow = Abuf + ((size_t)b * NPAD + m0 + w * 32) * TPAD;
  for (int kk = 0; kk < TPAD / 32; ++kk) {
    bf16x8 af[2], bfr[6];
    #pragma unroll
    for (int mi = 0; mi < 2; mi++)
      af[mi] = *(const bf16x8*)(Arow + (size_t)(mi * 16 + l15) * TPAD + kk * 32 + quad * 8);
    #pragma unroll
    for (int ni = 0; ni < 6; ni++)
      bfr[ni] = *(const bf16x8*)(P1T + (size_t)(ni * 16 + l15) * TPAD + kk * 32 + quad * 8);
    #pragma unroll
    for (int mi = 0; mi < 2; mi++)
      #pragma unroll
      for (int ni = 0; ni < 6; ni++)
        acc1[mi][ni] = __builtin_amdgcn_mfma_f32_16x16x32_bf16(af[mi], bfr[ni], acc1[mi][ni], 0, 0, 0);
  }

  #pragma unroll
  for (int mi = 0; mi < 2; mi++) {
    #pragma unroll
    for (int ni = 0; ni < 6; ni++) {
      float bias = P1b[ni * 16 + l15];
      #pragma unroll
      for (int r = 0; r < 4; r++) {
        float x = acc1[mi][ni][r] + bias;
        float t = 1.f - 2.f / (__expf(2.f * x) + 1.f);
        Hs[(w * 32 + mi * 16 + quad * 4 + r) * HS_STRIDE + ni * 16 + l15] = __float2bfloat16(t);
      }
    }
  }
  __syncthreads();

  #pragma unroll
  for (int half = 0; half < 2; ++half) {
    f32x4 acc2[2][6];
    #pragma unroll
    for (int i = 0; i < 2; i++)
      #pragma unroll
      for (int j = 0; j < 6; j++) acc2[i][j] = zero;

    #pragma unroll
    for (int kk = 0; kk < 3; ++kk) {
      bf16x8 af[2], bfr[6];
      #pragma unroll
      for (int mi = 0; mi < 2; mi++)
        af[mi] = *(const bf16x8*)(Hs + (w * 32 + mi * 16 + l15) * HS_STRIDE + kk * 32 + quad * 8);
      #pragma unroll
      for (int ni = 0; ni < 6; ni++)
        bfr[ni] = *(const bf16x8*)(P2T + (size_t)((half * 6 + ni) * 16 + l15) * P_ + kk * 32 + quad * 8);
      #pragma unroll
      for (int mi = 0; mi < 2; mi++)
        #pragma unroll
        for (int ni = 0; ni < 6; ni++)
          acc2[mi][ni] = __builtin_amdgcn_mfma_f32_16x16x32_bf16(af[mi], bfr[ni], acc2[mi][ni], 0, 0, 0);
    }

    #pragma unroll
    for (int mi = 0; mi < 2; mi++) {
      #pragma unroll
      for (int ni = 0; ni < 6; ni++) {
        int jj = (half * 6 + ni) * 16 + l15;
        float bias = P2b[jj];
        int pout = jj >> 1;
        #pragma unroll
        for (int r = 0; r < 4; r++) {
          int n = m0 + w * 32 + mi * 16 + quad * 4 + r;
          if (n < N_) {
            float s = acc2[mi][ni][r] + bias;
            size_t o = ((size_t)b * P_ + pout) * N_ + n;
            if ((jj & 1) == 0) {
              dout[o] = s;
            } else {
              float sp = (s > 20.f) ? s : log1pf(__expf(s));
              dout[(size_t)B_ * P_ * N_ + 1 + o] = sp + 1e-6f;
            }
          }
        }
      }
    }
  }
  if (b == 0 && blockIdx.x == 0 && tid == 0)
    dout[(size_t)B_ * P_ * N_] = loss_partial[0] + loss_partial[1];
}

// ----------------------------------------------------------------------------------
extern "C" void kernel_launch(void* const* d_in, const int* in_sizes, int n_in,
                              void* d_out, int out_size, void* d_ws, size_t ws_size,
                              hipStream_t stream) {
  const float* x   = (const float*)d_in[0];
  const float* Wg  = (const float*)d_in[11];
  const float* We1 = (const float*)d_in[12];
  const float* be1 = (const float*)d_in[13];
  const float* We2 = (const float*)d_in[14];
  const float* be2 = (const float*)d_in[15];
  const float* P1w = (const float*)d_in[16];
  const float* P1b = (const float*)d_in[17];
  const float* P2w = (const float*)d_in[18];
  const float* P2b = (const float*)d_in[19];

  char* ws = (char*)d_ws;
  size_t off = 0;
  auto alloc = [&](size_t bytes) -> void* {
    void* p = ws + off;
    off += (bytes + 255) & ~(size_t)255;
    return p;
  };
  float* out        = (float*)alloc((size_t)B_ * T_ * N_ * 4);
  bf16*  Abuf       = (bf16*) alloc((size_t)B_ * NPAD * TPAD * 2);
  bf16*  W1T        = (bf16*) alloc((size_t)L_ * E_ * F_ * TPAD * 2);
  bf16*  W2B        = (bf16*) alloc((size_t)L_ * E_ * 4 * 196608 * 2);
  bf16*  P1T        = (bf16*) alloc((size_t)P_ * TPAD * 2);
  bf16*  P2T        = (bf16*) alloc((size_t)2 * P_ * P_ * 2);
  bf16*  h          = (bf16*) alloc((size_t)B_ * 2 * 786432 * 2);
  float* colsum     = (float*)alloc((size_t)B_ * T_ * 4);
  int*   pair_e     = (int*)  alloc(B_ * 2 * 4);
  float* pair_gate  = (float*)alloc(B_ * 2 * 4);
  float* loss_part  = (float*)alloc(2 * 4);
  if (ws_size < off) return;  // workspace too small — bail instead of corrupting

  dim3 tb(32, 8);
  transpose_cast_kernel<<<dim3(11, 64, 8), tb, 0, stream>>>(
      We1, W1T, T_, F_, TPAD, F_, (long long)T_ * F_, (long long)F_ * TPAD);
  repack_w2_kernel<<<dim3(64, 4, 8), 256, 0, stream>>>(We2, W2B);
  transpose_cast_kernel<<<dim3(11, 3, 1), tb, 0, stream>>>(
      P1w, P1T, T_, P_, TPAD, P_, 0, 0);
  transpose_cast_kernel<<<dim3(3, 6, 1), tb, 0, stream>>>(
      P2w, P2T, P_, 2 * P_, P_, 2 * P_, 0, 0);

  revin_kernel<<<dim3(B_, 3), 128, 0, stream>>>(x, out, Abuf);

  for (int l = 0; l < L_; ++l) {
    gate1_kernel<<<dim3(21, B_), 256, 0, stream>>>(out, colsum);
    gate2_kernel<<<1, 128, 0, stream>>>(colsum, Wg, pair_e, pair_gate, loss_part, l);
    gemm1_kernel<<<dim3(16, 3, 64), 256, 0, stream>>>(Abuf, W1T, be1, pair_e, pair_gate, h, l);
    gemm2_kernel<<<768, 256, 0, stream>>>(h, W2B, be2, pair_e, pair_gate, out, Abuf, l);
  }

  proj_kernel<<<dim3(3, B_), 256, 0, stream>>>(Abuf, P1T, P1b, P2T, P2b, loss_part,
                                               (float*)d_out);
}